// Round 5
// baseline (3126.721 us; speedup 1.0000x reference)
//
#include <hip/hip_runtime.h>
#include <hip/hip_bf16.h>
#include <cstdint>
#include <cstddef>

#define T_LEN 512
#define B_SZ  512
#define F_IN  64
#define H_DIM 128
#define NSTEP 8

typedef __attribute__((ext_vector_type(8))) short short8;
typedef __attribute__((ext_vector_type(4))) float f32x4;

__device__ __forceinline__ float fsig(float x) { return 1.0f / (1.0f + __expf(-x)); }
__device__ __forceinline__ float ftanh(float x) {
  float e = __expf(-2.0f * fabsf(x));
  float t = (1.0f - e) / (1.0f + e);
  return copysignf(t, x);
}
__device__ __forceinline__ unsigned short bf16hi(float x) {
  __hip_bfloat16 h = __float2bfloat16(x);
  return *(unsigned short*)&h;
}
__device__ __forceinline__ float bf2f(unsigned short u) {
  return __uint_as_float(((unsigned)u) << 16);
}
__device__ __forceinline__ float bflo(unsigned u) { return __uint_as_float(u << 16); }
__device__ __forceinline__ float bfhi(unsigned u) { return __uint_as_float(u & 0xffff0000u); }

// lgkm-only barrier: LDS consistency without draining vmcnt (prefetch loads
// and flush stores stay in flight across steps).
__device__ __forceinline__ void step_barrier() {
  asm volatile("s_waitcnt lgkmcnt(0)" ::: "memory");
  __builtin_amdgcn_s_barrier();
  asm volatile("" ::: "memory");
}

// DPP cross-lane add within 16-lane rows (decoder scores)
template <int CTRL>
__device__ __forceinline__ float dpp_add(float v) {
  int p = __builtin_amdgcn_update_dpp(0, __float_as_int(v), CTRL, 0xF, 0xF, true);
  return v + __int_as_float(p);
}
__device__ __forceinline__ float row_sum16(float v) {
  v = dpp_add<0xB1>(v);
  v = dpp_add<0x4E>(v);
  v = dpp_add<0x124>(v);
  v = dpp_add<0x128>(v);
  return v;
}

// split 8 consecutive fp32 into bf16 hi/lo short8 fragments
__device__ __forceinline__ void split8(const float* p, short8& hi, short8& lo) {
  #pragma unroll
  for (int i = 0; i < 8; ++i) {
    const float v = p[i];
    const unsigned short h = bf16hi(v);
    hi[i] = (short)h;
    lo[i] = (short)bf16hi(v - bf2f(h));
  }
}

// split two adjacent float4 (8 fp32) into bf16 hi/lo short8 fragments
__device__ __forceinline__ void split_f4pair(const float4 a, const float4 b,
                                             short8& hi, short8& lo) {
  const float v[8] = {a.x, a.y, a.z, a.w, b.x, b.y, b.z, b.w};
  #pragma unroll
  for (int j = 0; j < 8; ++j) {
    const unsigned short h = bf16hi(v[j]);
    hi[j] = (short)h;
    lo[j] = (short)bf16hi(v[j] - bf2f(h));
  }
}

// -------------------------------------------------------------------------
// Split the 3 encoder w_ih matrices into bf16 hi/lo pairs (one-time prep).
// -------------------------------------------------------------------------
__global__ __launch_bounds__(256) void prep_split(
    const float* __restrict__ w0, const float* __restrict__ w1,
    const float* __restrict__ w2,
    unsigned short* __restrict__ hi, unsigned short* __restrict__ lo)
{
  const int i = blockIdx.x * 256 + threadIdx.x;
  if (i >= 122880) return;
  float v = (i < 24576) ? w0[i] : ((i < 73728) ? w1[i - 24576] : w2[i - 73728]);
  const unsigned short h = bf16hi(v);
  hi[i] = h;
  lo[i] = bf16hi(v - bf2f(h));
}

// -------------------------------------------------------------------------
// Fused GRU layer v4.1: identical to v4 except the epilogue flush bug fix.
// The gx (input GEMM) work for group g+1 is statically spread across the 8
// recurrence steps of group g — its MFMAs/loads fill the gh chain's stall
// cycles; no serial boundary phase remains.
//  - w_hh hi/lo persistent in 96 VGPRs (only persistent fragment set)
//  - w_ih hi in swizzled LDS; w_ih lo streamed from global 1-2 steps ahead
//  - X loaded direct global->reg (64B-granule coalesced), no LDS staging
//  - gxlds double-buffered; steps read 6 gate floats via ds_read
//  - all-lane A-fragment reads (row = l16&1): C rows 2-15 are garbage but
//    never read; kills divergence + zero-fragment registers
//  - lgkm-only step barriers: prefetch stays in flight (counted-vmcnt style)
//  - H history in 2 half-group (4-step) LDS buffers, flushed coalesced:
//    half 0 (steps 0-3) at tt==4, half 1 (steps 4-7) at tt==0 of the next
//    group; EPILOGUE must flush half 1 at tp = 63*8+4 = 508 (v4 bug: 504).
// -------------------------------------------------------------------------
template <int IS_L0>
__global__ __launch_bounds__(512, 1) void rec_fused(
    const float* x,                         // layer0 input (B,T,F), else unused
    const unsigned short* Xhi,              // layers>=1: prev-layer H hi (T,B,H)
    const unsigned short* Xlo,
    const unsigned short* __restrict__ Wih_hi,  // (384, KD) bf16 hi
    const unsigned short* __restrict__ Wih_lo,  // (384, KD) bf16 lo
    const float* __restrict__ w_hh, const float* __restrict__ b_ih,
    const float* __restrict__ b_hh,
    unsigned short* Hhi, unsigned short* Hlo)   // out (T,B,H)
{
  constexpr int KD    = IS_L0 ? 64 : 128;
  constexpr int NCK   = KD / 32;
  constexpr int WROW  = KD * 2;             // bytes per W row in LDS
  constexpr int WGRAN = WROW / 16;          // 16B granules per W row

  __shared__ unsigned short Wlds[384 * KD];       // w_ih hi, swizzled
  __shared__ float gxlds[2][6144];                // double-buffered group gx
  __shared__ unsigned short hb_h[2048], hb_l[2048]; // 2 half-group h buffers
  __shared__ unsigned short hsh[2][256], hsl[2][256]; // h double buffer

  const int tid  = threadIdx.x;
  const int wv   = tid >> 6, lane = tid & 63;
  const int quad = lane >> 4, l16 = lane & 15;
  const int b0   = blockIdx.x * 2;
  const int c    = wv * 16 + l16;          // owned channel (quad-0 lanes)

  // ---- stage w_ih hi into LDS (swizzled: granule ^= row&7) ----
  {
    unsigned char* wb = (unsigned char*)Wlds;
    #pragma unroll
    for (int k = 0; k < (384 * WGRAN) / 512; ++k) {
      const int idx = k * 512 + tid;
      const int row = idx / WGRAN;
      const int gg  = idx % WGRAN;
      const uint4 v = *(const uint4*)&Wih_hi[(size_t)row * KD + gg * 8];
      *(uint4*)&wb[row * WROW + ((gg ^ (row & 7)) * 16)] = v;
    }
  }

  // ---- w_hh persistent fragments (split from fp32) ----
  short8 Bh[3][4], Bl[3][4];
  #pragma unroll
  for (int g_ = 0; g_ < 3; ++g_)
    #pragma unroll
    for (int ck = 0; ck < 4; ++ck)
      split8(&w_hh[(size_t)(g_ * 128 + c) * 128 + ck * 32 + quad * 8],
             Bh[g_][ck], Bl[g_][ck]);

  float bias_r = 0.f, bias_z = 0.f, bihn = 0.f, bhhn = 0.f, h0 = 0.f, h1 = 0.f;
  if (quad == 0) {
    bias_r = b_ih[c] + b_hh[c];
    bias_z = b_ih[c + 128] + b_hh[c + 128];
    bihn = b_ih[c + 256];
    bhhn = b_hh[c + 256];
    hsh[0][c] = 0; hsh[0][128 + c] = 0;
    hsl[0][c] = 0; hsl[0][128 + c] = 0;
  }

  const f32x4 z4 = (f32x4){0.f, 0.f, 0.f, 0.f};
  f32x4 ax[3][2];
  #pragma unroll
  for (int g_ = 0; g_ < 3; ++g_) { ax[g_][0] = z4; ax[g_][1] = z4; }

  // ---- gx-side register state ----
  uint4  xh[4], xl[4];      // KD=128 X fragments (bf16 hi/lo)
  float4 xf[4];             // KD=64 fp32 X
  short8 xhf2[2], xlf2[2];  // KD=64 split results
  short8 wloA[NCK], wloB[NCK];

  auto load_x_pair = [&](int tgn, int ck0_) {   // KD=128: 2 ck, hi+lo
    #pragma unroll
    for (int d = 0; d < 2; ++d) {
      const int ck = ck0_ + d;
      const size_t base =
          ((size_t)(tgn + (l16 >> 1)) * B_SZ + b0 + (l16 & 1)) * 128 + ck * 32 + quad * 8;
      xh[ck] = *(const uint4*)&Xhi[base];
      xl[ck] = *(const uint4*)&Xlo[base];
    }
  };
  auto load_xf_ck = [&](int tgn, int ck) {      // KD=64: 2 float4
    const size_t base =
        ((size_t)(b0 + (l16 & 1)) * T_LEN + tgn + (l16 >> 1)) * 64 + ck * 32 + quad * 8;
    xf[ck * 2]     = *(const float4*)&x[base];
    xf[ck * 2 + 1] = *(const float4*)&x[base + 4];
  };
  auto load_wlo = [&](int g_, short8* dst) {
    #pragma unroll
    for (int ck = 0; ck < NCK; ++ck)
      dst[ck] = *(const short8*)&Wih_lo[(size_t)(g_ * 128 + c) * KD + ck * 32 + quad * 8];
  };
  const unsigned char* wbase = (const unsigned char*)Wlds;
  auto gx3 = [&](int g_, int ck, const short8 xhfv, const short8 xlfv, const short8 wlov) {
    const int gran = (ck * 4 + quad) ^ (c & 7);
    const short8 wh = *(const short8*)&wbase[(g_ * 128 + c) * WROW + gran * 16];
    const int p = (NCK == 4) ? (ck >> 1) : ck;
    ax[g_][p] = __builtin_amdgcn_mfma_f32_16x16x32_bf16(xhfv, wh,   ax[g_][p], 0, 0, 0);
    ax[g_][p] = __builtin_amdgcn_mfma_f32_16x16x32_bf16(xhfv, wlov, ax[g_][p], 0, 0, 0);
    ax[g_][p] = __builtin_amdgcn_mfma_f32_16x16x32_bf16(xlfv, wh,   ax[g_][p], 0, 0, 0);
  };
  auto gx_write = [&](int g_, float* dst) {
    #pragma unroll
    for (int reg = 0; reg < 4; ++reg) {
      const int tt_ = quad * 2 + (reg >> 1), r_ = reg & 1;
      dst[(tt_ * 2 + r_) * 384 + g_ * 128 + c] = ax[g_][0][reg] + ax[g_][1][reg];
    }
    ax[g_][0] = z4; ax[g_][1] = z4;
  };
  auto flush_half = [&](int half, int tp) {  // 4 steps x 2 rows x 128 ch
    const int t8 = tid & 255;
    const int o  = t8 * 4;
    const int tt_ = o >> 8, rem = o & 255;
    const int r_ = rem >> 7, c_ = rem & 127;
    const size_t go = ((size_t)(tp + tt_) * B_SZ + b0 + r_) * 128 + c_;
    const int lo_ = half * 1024 + tt_ * 256 + r_ * 128 + c_;
    if (tid < 256) *(uint2*)&Hhi[go] = *(const uint2*)&hb_h[lo_];
    else           *(uint2*)&Hlo[go] = *(const uint2*)&hb_l[lo_];
  };

  // ---- prologue: compute gx[0] serially into gxlds[0] ----
  if constexpr (IS_L0) { load_xf_ck(0, 0); load_xf_ck(0, 1); }
  else { load_x_pair(0, 0); load_x_pair(0, 2); }
  load_wlo(0, wloA);
  load_wlo(1, wloB);
  __syncthreads();   // Wlds + hs zeros visible

  if constexpr (IS_L0) {
    split_f4pair(xf[0], xf[1], xhf2[0], xlf2[0]);
    split_f4pair(xf[2], xf[3], xhf2[1], xlf2[1]);
    gx3(0, 0, xhf2[0], xlf2[0], wloA[0]);
    gx3(0, 1, xhf2[1], xlf2[1], wloA[1]);
    load_wlo(2, wloA);
    gx3(1, 0, xhf2[0], xlf2[0], wloB[0]);
    gx3(1, 1, xhf2[1], xlf2[1], wloB[1]);
    gx3(2, 0, xhf2[0], xlf2[0], wloA[0]);
    gx3(2, 1, xhf2[1], xlf2[1], wloA[1]);
  } else {
    gx3(0, 0, *(const short8*)&xh[0], *(const short8*)&xl[0], wloA[0]);
    gx3(0, 1, *(const short8*)&xh[1], *(const short8*)&xl[1], wloA[1]);
    gx3(0, 2, *(const short8*)&xh[2], *(const short8*)&xl[2], wloA[2]);
    gx3(0, 3, *(const short8*)&xh[3], *(const short8*)&xl[3], wloA[3]);
    load_wlo(2, wloA);
    gx3(1, 0, *(const short8*)&xh[0], *(const short8*)&xl[0], wloB[0]);
    gx3(1, 1, *(const short8*)&xh[1], *(const short8*)&xl[1], wloB[1]);
    gx3(1, 2, *(const short8*)&xh[2], *(const short8*)&xl[2], wloB[2]);
    gx3(1, 3, *(const short8*)&xh[3], *(const short8*)&xl[3], wloB[3]);
    gx3(2, 0, *(const short8*)&xh[0], *(const short8*)&xl[0], wloA[0]);
    gx3(2, 1, *(const short8*)&xh[1], *(const short8*)&xl[1], wloA[1]);
    gx3(2, 2, *(const short8*)&xh[2], *(const short8*)&xl[2], wloA[2]);
    gx3(2, 3, *(const short8*)&xh[3], *(const short8*)&xl[3], wloA[3]);
  }
  gx_write(0, &gxlds[0][0]);
  gx_write(1, &gxlds[0][0]);
  gx_write(2, &gxlds[0][0]);
  __syncthreads();

  // ---- main loop: 64 groups x 8 steps, fully pipelined ----
  for (int g = 0; g < 64; ++g) {
    const int gn = g + 1;
    const bool live = (gn < 64);
    const float* gxr = &gxlds[g & 1][0];
    float* gxw = &gxlds[gn & 1][0];
    #pragma unroll
    for (int tt = 0; tt < 8; ++tt) {
      // --- scheduled prefetch / flush (issue early, no vmcnt drain) ---
      if (tt == 0) {
        if (g > 0) flush_half(1, g * 8 - 4);
        if (live) {
          if constexpr (IS_L0) load_xf_ck(gn * 8, 0);
          else load_x_pair(gn * 8, 0);
        }
      }
      if (tt == 1 && live) {
        if constexpr (IS_L0) load_xf_ck(gn * 8, 1);
        else load_x_pair(gn * 8, 2);
        load_wlo(0, wloA);
      }
      if (tt == 3 && live) load_wlo(1, wloB);
      if (tt == 4) flush_half(0, g * 8);
      if (tt == 5 && live) load_wlo(2, wloA);

      // --- gate gx inputs (quad0) ---
      float gr0 = 0.f, gz0 = 0.f, gn0v = 0.f, gr1 = 0.f, gz1 = 0.f, gn1v = 0.f;
      if (quad == 0) {
        const float* gp = gxr + tt * 768 + c;
        gr0 = gp[0];   gz0 = gp[128]; gn0v = gp[256];
        gr1 = gp[384]; gz1 = gp[512]; gn1v = gp[640];
      }

      // --- h A-fragments: all lanes read row l16&1 (rows>=2 of C unused) ---
      short8 Ahf[4], Alf[4];
      #pragma unroll
      for (int ck = 0; ck < 4; ++ck) {
        const int ad = (l16 & 1) * 128 + ck * 32 + quad * 8;
        Ahf[ck] = *(const short8*)&hsh[tt & 1][ad];
        Alf[ck] = *(const short8*)&hsl[tt & 1][ad];
      }

      // --- gh MFMAs: 6 chains of 6, C-init from shared zero ---
      f32x4 acc[3][2];
      #pragma unroll
      for (int g_ = 0; g_ < 3; ++g_) {
        #pragma unroll
        for (int p = 0; p < 2; ++p) {
          const int k0 = p * 2;
          acc[g_][p] = __builtin_amdgcn_mfma_f32_16x16x32_bf16(Ahf[k0], Bh[g_][k0], z4, 0, 0, 0);
          acc[g_][p] = __builtin_amdgcn_mfma_f32_16x16x32_bf16(Ahf[k0], Bl[g_][k0], acc[g_][p], 0, 0, 0);
          acc[g_][p] = __builtin_amdgcn_mfma_f32_16x16x32_bf16(Alf[k0], Bh[g_][k0], acc[g_][p], 0, 0, 0);
          acc[g_][p] = __builtin_amdgcn_mfma_f32_16x16x32_bf16(Ahf[k0+1], Bh[g_][k0+1], acc[g_][p], 0, 0, 0);
          acc[g_][p] = __builtin_amdgcn_mfma_f32_16x16x32_bf16(Ahf[k0+1], Bl[g_][k0+1], acc[g_][p], 0, 0, 0);
          acc[g_][p] = __builtin_amdgcn_mfma_f32_16x16x32_bf16(Alf[k0+1], Bh[g_][k0+1], acc[g_][p], 0, 0, 0);
        }
      }

      // --- pipelined gx MFMAs for group g+1 (independent of gh) ---
      if (live) {
        if constexpr (IS_L0) {
          if (tt == 1) split_f4pair(xf[0], xf[1], xhf2[0], xlf2[0]);
          if (tt == 2) {
            split_f4pair(xf[2], xf[3], xhf2[1], xlf2[1]);
            gx3(0, 0, xhf2[0], xlf2[0], wloA[0]);
            gx3(0, 1, xhf2[1], xlf2[1], wloA[1]);
          }
          if (tt == 4) { gx3(1, 0, xhf2[0], xlf2[0], wloB[0]);
                         gx3(1, 1, xhf2[1], xlf2[1], wloB[1]); }
          if (tt == 6) { gx3(2, 0, xhf2[0], xlf2[0], wloA[0]);
                         gx3(2, 1, xhf2[1], xlf2[1], wloA[1]); }
        } else {
          if (tt == 2) { gx3(0, 0, *(const short8*)&xh[0], *(const short8*)&xl[0], wloA[0]);
                         gx3(0, 1, *(const short8*)&xh[1], *(const short8*)&xl[1], wloA[1]); }
          if (tt == 3) { gx3(0, 2, *(const short8*)&xh[2], *(const short8*)&xl[2], wloA[2]);
                         gx3(0, 3, *(const short8*)&xh[3], *(const short8*)&xl[3], wloA[3]); }
          if (tt == 4) { gx3(1, 0, *(const short8*)&xh[0], *(const short8*)&xl[0], wloB[0]);
                         gx3(1, 1, *(const short8*)&xh[1], *(const short8*)&xl[1], wloB[1]); }
          if (tt == 5) { gx3(1, 2, *(const short8*)&xh[2], *(const short8*)&xl[2], wloB[2]);
                         gx3(1, 3, *(const short8*)&xh[3], *(const short8*)&xl[3], wloB[3]); }
          if (tt == 6) { gx3(2, 0, *(const short8*)&xh[0], *(const short8*)&xl[0], wloA[0]);
                         gx3(2, 1, *(const short8*)&xh[1], *(const short8*)&xl[1], wloA[1]); }
          if (tt == 7) { gx3(2, 2, *(const short8*)&xh[2], *(const short8*)&xl[2], wloA[2]);
                         gx3(2, 3, *(const short8*)&xh[3], *(const short8*)&xl[3], wloA[3]); }
        }
        if (tt == 4) gx_write(0, gxw);
        if (tt == 6) gx_write(1, gxw);
        if (tt == 7) gx_write(2, gxw);
      }

      // --- gates (quad0): gh for channel c rows 0,1 are regs 0,1 ---
      if (quad == 0) {
        const float ghr0 = acc[0][0][0] + acc[0][1][0];
        const float ghr1 = acc[0][0][1] + acc[0][1][1];
        const float ghz0 = acc[1][0][0] + acc[1][1][0];
        const float ghz1 = acc[1][0][1] + acc[1][1][1];
        const float ghn0 = acc[2][0][0] + acc[2][1][0];
        const float ghn1 = acc[2][0][1] + acc[2][1][1];
        const float r0 = fsig(gr0 + ghr0 + bias_r);
        const float z0 = fsig(gz0 + ghz0 + bias_z);
        const float nv0 = ftanh(gn0v + bihn + r0 * (ghn0 + bhhn));
        const float hn0 = (1.0f - z0) * nv0 + z0 * h0;
        const float r1 = fsig(gr1 + ghr1 + bias_r);
        const float z1 = fsig(gz1 + ghz1 + bias_z);
        const float nv1 = ftanh(gn1v + bihn + r1 * (ghn1 + bhhn));
        const float hn1 = (1.0f - z1) * nv1 + z1 * h1;
        h0 = hn0; h1 = hn1;
        const int nb = (tt + 1) & 1;
        const unsigned short hh0 = bf16hi(hn0), hh1 = bf16hi(hn1);
        const unsigned short hl0 = bf16hi(hn0 - bf2f(hh0));
        const unsigned short hl1 = bf16hi(hn1 - bf2f(hh1));
        hsh[nb][c] = hh0;       hsh[nb][128 + c] = hh1;
        hsl[nb][c] = hl0;       hsl[nb][128 + c] = hl1;
        const int hb = (tt >> 2) * 1024 + (tt & 3) * 256 + c;
        hb_h[hb] = hh0;       hb_h[hb + 128] = hh1;
        hb_l[hb] = hl0;       hb_l[hb + 128] = hl1;
      }
      step_barrier();
    }
  }
  // final flush: second half of group 63 = timesteps 508..511
  // (v4 bug: tp was 504, which re-wrote t 504-507 with steps 4-7's data and
  //  left t 508-511 holding the previous layer's values)
  flush_half(1, 508);
}

// -------------------------------------------------------------------------
// keys = H @ aWk^T + abk, split-bf16 MFMA, output Khi (bf16 RNE) only.
// -------------------------------------------------------------------------
__global__ __launch_bounds__(256) void keys_gemm(
    const unsigned short* __restrict__ Ahi, const unsigned short* __restrict__ Alo,
    const float* __restrict__ aWk, const float* __restrict__ abk,
    unsigned short* __restrict__ Khi)
{
  __shared__ unsigned short Ah[64 * 40], Al[64 * 40];
  __shared__ unsigned short Bh[128 * 136], Bl[128 * 136];
  const int tid  = threadIdx.x;
  const int wave = tid >> 6, lane = tid & 63;
  const int quad = lane >> 4, l16 = lane & 15;
  const size_t m0 = (size_t)blockIdx.x * 64;

  for (int i = tid; i < 16384; i += 256) {
    const float v = aWk[i];
    const unsigned short h = bf16hi(v);
    const int r = i >> 7, k = i & 127;
    Bh[r * 136 + k] = h;
    Bl[r * 136 + k] = bf16hi(v - bf2f(h));
  }

  f32x4 acc[8];
  #pragma unroll
  for (int i = 0; i < 8; ++i) acc[i] = (f32x4){0.f, 0.f, 0.f, 0.f};
  float bias[8];
  #pragma unroll
  for (int nt = 0; nt < 8; ++nt) bias[nt] = abk[nt * 16 + l16];

  const int r = tid >> 2, c8 = (tid & 3) * 8;
  for (int kc = 0; kc < 128; kc += 32) {
    __syncthreads();
    const size_t src = (m0 + r) * 128 + kc + c8;
    *(uint4*)&Ah[r * 40 + c8] = *(const uint4*)&Ahi[src];
    *(uint4*)&Al[r * 40 + c8] = *(const uint4*)&Alo[src];
    __syncthreads();
    const short8 a_hi = *(const short8*)&Ah[(wave * 16 + l16) * 40 + quad * 8];
    const short8 a_lo = *(const short8*)&Al[(wave * 16 + l16) * 40 + quad * 8];
    #pragma unroll
    for (int nt = 0; nt < 8; ++nt) {
      const short8 b_hi = *(const short8*)&Bh[(nt * 16 + l16) * 136 + kc + quad * 8];
      const short8 b_lo = *(const short8*)&Bl[(nt * 16 + l16) * 136 + kc + quad * 8];
      acc[nt] = __builtin_amdgcn_mfma_f32_16x16x32_bf16(a_hi, b_hi, acc[nt], 0, 0, 0);
      acc[nt] = __builtin_amdgcn_mfma_f32_16x16x32_bf16(a_hi, b_lo, acc[nt], 0, 0, 0);
      acc[nt] = __builtin_amdgcn_mfma_f32_16x16x32_bf16(a_lo, b_hi, acc[nt], 0, 0, 0);
    }
  }
  #pragma unroll
  for (int nt = 0; nt < 8; ++nt) {
    #pragma unroll
    for (int reg = 0; reg < 4; ++reg) {
      const size_t m = m0 + wave * 16 + quad * 4 + reg;
      const int n = nt * 16 + l16;
      Khi[m * 128 + n] = bf16hi(acc[nt][reg] + bias[nt]);
    }
  }
}

// -------------------------------------------------------------------------
// Decoder (R7): one block per batch row, 512 threads, 8 steps in-kernel.
// -------------------------------------------------------------------------
__global__ __launch_bounds__(512) void decoder(
    const unsigned short* __restrict__ Hhi, const unsigned short* __restrict__ Hlo,
    const unsigned short* __restrict__ Khi,
    const float* __restrict__ aWq, const float* __restrict__ abq,
    const float* __restrict__ av,
    const float* __restrict__ dwih, const float* __restrict__ dwhh,
    const float* __restrict__ dbih, const float* __restrict__ dbhh,
    const float* __restrict__ lng, const float* __restrict__ lnb,
    const float* __restrict__ w1, const float* __restrict__ b1,
    const float* __restrict__ w2, const float* __restrict__ b2,
    float* __restrict__ out)
{
  __shared__ float h_s[128], q_s[128], av_s[128], s_s[512], w_s[512];
  __shared__ float part[8][128], u_s[256], gx_s[384], gh_s[384], y_s[128];
  __shared__ float red[16];
  const int b = blockIdx.x, tid = threadIdx.x;
  const int wave = tid >> 6, lane = tid & 63;
  const int tslot = lane >> 4, ks = lane & 15;

  if (tid < 128) {
    const size_t base = ((size_t)(T_LEN - 1) * B_SZ + b) * 128 + tid;
    h_s[tid] = bf2f(Hhi[base]) + bf2f(Hlo[base]);
    av_s[tid] = av[tid];
  }
  __syncthreads();

  for (int step = 0; step < NSTEP; ++step) {
    if (tid < 128) {
      float acc = abq[tid];
      const float* wr = &aWq[(size_t)tid * 128];
      #pragma unroll 8
      for (int k4 = 0; k4 < 32; ++k4) {
        const float4 hv = *(const float4*)&h_s[k4 * 4];
        const float4 wv = *(const float4*)&wr[k4 * 4];
        acc += hv.x * wv.x + hv.y * wv.y + hv.z * wv.z + hv.w * wv.w;
      }
      q_s[tid] = acc;
    }
    __syncthreads();
    #pragma unroll 2
    for (int it = 0; it < 16; ++it) {
      const int t = it * 32 + wave * 4 + tslot;
      const size_t kb = ((size_t)t * B_SZ + b) * 128 + ks * 8;
      const uint4 uh = *(const uint4*)&Khi[kb];
      const float4 q0 = *(const float4*)&q_s[ks * 8];
      const float4 q1 = *(const float4*)&q_s[ks * 8 + 4];
      const float4 a0 = *(const float4*)&av_s[ks * 8];
      const float4 a1 = *(const float4*)&av_s[ks * 8 + 4];
      float acc = ftanh(bflo(uh.x) + q0.x) * a0.x + ftanh(bfhi(uh.x) + q0.y) * a0.y
                + ftanh(bflo(uh.y) + q0.z) * a0.z + ftanh(bfhi(uh.y) + q0.w) * a0.w
                + ftanh(bflo(uh.z) + q1.x) * a1.x + ftanh(bfhi(uh.z) + q1.y) * a1.y
                + ftanh(bflo(uh.w) + q1.z) * a1.z + ftanh(bfhi(uh.w) + q1.w) * a1.w;
      acc = row_sum16(acc);
      if (ks == 0) s_s[t] = acc;
    }
    __syncthreads();
    {
      const float sv = s_s[tid];
      float mx = sv;
      #pragma unroll
      for (int o = 32; o; o >>= 1) mx = fmaxf(mx, __shfl_xor(mx, o, 64));
      if (lane == 0) red[wave] = mx;
      __syncthreads();
      mx = red[0];
      #pragma unroll
      for (int i = 1; i < 8; ++i) mx = fmaxf(mx, red[i]);
      const float e = __expf(sv - mx);
      float sm = e;
      #pragma unroll
      for (int o = 32; o; o >>= 1) sm += __shfl_xor(sm, o, 64);
      if (lane == 0) red[8 + wave] = sm;
      __syncthreads();
      float tot = red[8];
      #pragma unroll
      for (int i = 1; i < 8; ++i) tot += red[8 + i];
      w_s[tid] = e / tot;
    }
    __syncthreads();
    {
      const int th = tid >> 6;
      const int c2 = (tid & 63) * 2;
      float acc0 = 0.0f, acc1 = 0.0f;
      #pragma unroll 4
      for (int q = 0; q < 64; ++q) {
        const int t = th * 64 + q;
        const unsigned u = *(const unsigned*)&Hhi[((size_t)t * B_SZ + b) * 128 + c2];
        const float wt = w_s[t];
        acc0 += wt * bflo(u);
        acc1 += wt * bfhi(u);
      }
      part[th][c2] = acc0;
      part[th][c2 + 1] = acc1;
    }
    __syncthreads();
    if (tid < 128) {
      float s = part[0][tid];
      #pragma unroll
      for (int i = 1; i < 8; ++i) s += part[i][tid];
      u_s[tid] = s;
      u_s[128 + tid] = h_s[tid];
    }
    __syncthreads();
    if (tid < 384) {
      const int j = tid;
      float gxv = dbih[j], ghv = dbhh[j];
      const float* wxr = &dwih[(size_t)j * 256];
      const float* whr = &dwhh[(size_t)j * 128];
      #pragma unroll 8
      for (int k4 = 0; k4 < 64; ++k4) {
        const float4 uv = *(const float4*)&u_s[k4 * 4];
        const float4 wv = *(const float4*)&wxr[k4 * 4];
        gxv += uv.x * wv.x + uv.y * wv.y + uv.z * wv.z + uv.w * wv.w;
      }
      #pragma unroll 8
      for (int k4 = 0; k4 < 32; ++k4) {
        const float4 hv = *(const float4*)&h_s[k4 * 4];
        const float4 wv = *(const float4*)&whr[k4 * 4];
        ghv += hv.x * wv.x + hv.y * wv.y + hv.z * wv.z + hv.w * wv.w;
      }
      gx_s[j] = gxv; gh_s[j] = ghv;
    }
    __syncthreads();
    if (tid < 128) {
      const float r = fsig(gx_s[tid] + gh_s[tid]);
      const float z = fsig(gx_s[128 + tid] + gh_s[128 + tid]);
      const float n = ftanh(gx_s[256 + tid] + r * gh_s[256 + tid]);
      const float hn = (1.0f - z) * n + z * h_s[tid];
      h_s[tid] = hn;
      float s1 = hn, s2 = hn * hn;
      #pragma unroll
      for (int o = 32; o; o >>= 1) { s1 += __shfl_xor(s1, o, 64); s2 += __shfl_xor(s2, o, 64); }
      if ((tid & 63) == 0) { red[tid >> 6] = s1; red[4 + (tid >> 6)] = s2; }
    }
    __syncthreads();
    if (tid < 128) {
      const float hn  = h_s[tid];
      const float mu  = (red[0] + red[1]) * (1.0f / 128.0f);
      const float var = (red[4] + red[5]) * (1.0f / 128.0f) - mu * mu;
      y_s[tid] = (hn - mu) / sqrtf(var + 1e-5f) * lng[tid] + lnb[tid];
    }
    __syncthreads();
    if (tid < 64) {
      float acc = b1[tid];
      const float* wr = &w1[(size_t)tid * 128];
      #pragma unroll 8
      for (int k4 = 0; k4 < 32; ++k4) {
        const float4 yv = *(const float4*)&y_s[k4 * 4];
        const float4 wv = *(const float4*)&wr[k4 * 4];
        acc += yv.x * wv.x + yv.y * wv.y + yv.z * wv.z + yv.w * wv.w;
      }
      acc = fmaxf(acc, 0.0f);
      float v = acc * w2[tid];
      #pragma unroll
      for (int o = 32; o; o >>= 1) v += __shfl_xor(v, o, 64);
      if (tid == 0) out[(size_t)b * NSTEP + step] = v + b2[0];
    }
    __syncthreads();
  }
}

// -------------------------------------------------------------------------
extern "C" void kernel_launch(void* const* d_in, const int* in_sizes, int n_in,
                              void* d_out, int out_size, void* d_ws, size_t ws_size,
                              hipStream_t stream)
{
  (void)in_sizes; (void)n_in; (void)out_size; (void)ws_size;
  const float* x    = (const float*)d_in[0];
  const float* ewih[3] = {(const float*)d_in[1], (const float*)d_in[5], (const float*)d_in[9]};
  const float* ewhh[3] = {(const float*)d_in[2], (const float*)d_in[6], (const float*)d_in[10]};
  const float* ebih[3] = {(const float*)d_in[3], (const float*)d_in[7], (const float*)d_in[11]};
  const float* ebhh[3] = {(const float*)d_in[4], (const float*)d_in[8], (const float*)d_in[12]};
  const float* aWq  = (const float*)d_in[13];
  const float* abq  = (const float*)d_in[14];
  const float* aWk  = (const float*)d_in[15];
  const float* abk  = (const float*)d_in[16];
  const float* av   = (const float*)d_in[17];
  const float* dwih = (const float*)d_in[18];
  const float* dwhh = (const float*)d_in[19];
  const float* dbih = (const float*)d_in[20];
  const float* dbhh = (const float*)d_in[21];
  const float* lng  = (const float*)d_in[22];
  const float* lnb  = (const float*)d_in[23];
  const float* w1   = (const float*)d_in[24];
  const float* b1   = (const float*)d_in[25];
  const float* w2   = (const float*)d_in[26];
  const float* b2   = (const float*)d_in[27];

  const size_t HN = (size_t)T_LEN * B_SZ * H_DIM;               // 33,554,432 elems
  unsigned short* Hhi = (unsigned short*)d_ws;                  // 64 MiB (T,B,H)
  unsigned short* Hlo = Hhi + HN;                               // 64 MiB
  float* regionC = (float*)(Hlo + HN);                          // 128 MiB
  unsigned short* Whi = (unsigned short*)(regionC + 25165824 + 65536);
  unsigned short* Wlo = Whi + 122880;
  unsigned short* Khi = (unsigned short*)regionC;               // decode: 64 MiB

  prep_split<<<dim3(480), dim3(256), 0, stream>>>(ewih[0], ewih[1], ewih[2], Whi, Wlo);

  rec_fused<1><<<dim3(256), dim3(512), 0, stream>>>(
      x, nullptr, nullptr, Whi, Wlo,
      ewhh[0], ebih[0], ebhh[0], Hhi, Hlo);
  rec_fused<0><<<dim3(256), dim3(512), 0, stream>>>(
      nullptr, Hhi, Hlo, Whi + 24576, Wlo + 24576,
      ewhh[1], ebih[1], ebhh[1], Hhi, Hlo);
  rec_fused<0><<<dim3(256), dim3(512), 0, stream>>>(
      nullptr, Hhi, Hlo, Whi + 73728, Wlo + 73728,
      ewhh[2], ebih[2], ebhh[2], Hhi, Hlo);

  keys_gemm<<<dim3(4096), dim3(256), 0, stream>>>(Hhi, Hlo, aWk, abk, Khi);
  decoder<<<dim3(512), dim3(512), 0, stream>>>(
      Hhi, Hlo, Khi, aWq, abq, av, dwih, dwhh, dbih, dbhh,
      lng, lnb, w1, b1, w2, b2, (float*)d_out);
}

// Round 6
// 2629.842 us; speedup vs baseline: 1.1889x; 1.1889x over previous
//
#include <hip/hip_runtime.h>
#include <hip/hip_bf16.h>
#include <cstdint>
#include <cstddef>

#define T_LEN 512
#define B_SZ  512
#define F_IN  64
#define H_DIM 128
#define NSTEP 8

typedef __attribute__((ext_vector_type(8))) short short8;
typedef __attribute__((ext_vector_type(4))) float f32x4;

__device__ __forceinline__ float fsig(float x) { return 1.0f / (1.0f + __expf(-x)); }
__device__ __forceinline__ float ftanh(float x) {
  float e = __expf(-2.0f * fabsf(x));
  float t = (1.0f - e) / (1.0f + e);
  return copysignf(t, x);
}
__device__ __forceinline__ unsigned short bf16hi(float x) {
  __hip_bfloat16 h = __float2bfloat16(x);
  return *(unsigned short*)&h;
}
__device__ __forceinline__ float bf2f(unsigned short u) {
  return __uint_as_float(((unsigned)u) << 16);
}
__device__ __forceinline__ float bflo(unsigned u) { return __uint_as_float(u << 16); }
__device__ __forceinline__ float bfhi(unsigned u) { return __uint_as_float(u & 0xffff0000u); }

// lgkm-only barrier: LDS consistency without draining vmcnt (flush stores and
// prefetch loads stay in flight across steps; loads are consumed via the
// compiler's data-dependent vmcnt waits).
__device__ __forceinline__ void step_barrier() {
  asm volatile("s_waitcnt lgkmcnt(0)" ::: "memory");
  __builtin_amdgcn_s_barrier();
  asm volatile("" ::: "memory");
}

// DPP cross-lane add within 16-lane rows (decoder scores)
template <int CTRL>
__device__ __forceinline__ float dpp_add(float v) {
  int p = __builtin_amdgcn_update_dpp(0, __float_as_int(v), CTRL, 0xF, 0xF, true);
  return v + __int_as_float(p);
}
__device__ __forceinline__ float row_sum16(float v) {
  v = dpp_add<0xB1>(v);
  v = dpp_add<0x4E>(v);
  v = dpp_add<0x124>(v);
  v = dpp_add<0x128>(v);
  return v;
}

// split 8 consecutive fp32 into bf16 hi/lo short8 fragments
__device__ __forceinline__ void split8(const float* p, short8& hi, short8& lo) {
  #pragma unroll
  for (int i = 0; i < 8; ++i) {
    const float v = p[i];
    const unsigned short h = bf16hi(v);
    hi[i] = (short)h;
    lo[i] = (short)bf16hi(v - bf2f(h));
  }
}

// split two adjacent float4 (8 fp32) into bf16 hi/lo short8 fragments
__device__ __forceinline__ void split_f4pair(const float4 a, const float4 b,
                                             short8& hi, short8& lo) {
  const float v[8] = {a.x, a.y, a.z, a.w, b.x, b.y, b.z, b.w};
  #pragma unroll
  for (int j = 0; j < 8; ++j) {
    const unsigned short h = bf16hi(v[j]);
    hi[j] = (short)h;
    lo[j] = (short)bf16hi(v[j] - bf2f(h));
  }
}

// -------------------------------------------------------------------------
// Split the 3 encoder w_ih matrices into bf16 hi/lo pairs (one-time prep).
// -------------------------------------------------------------------------
__global__ __launch_bounds__(256) void prep_split(
    const float* __restrict__ w0, const float* __restrict__ w1,
    const float* __restrict__ w2,
    unsigned short* __restrict__ hi, unsigned short* __restrict__ lo)
{
  const int i = blockIdx.x * 256 + threadIdx.x;
  if (i >= 122880) return;
  float v = (i < 24576) ? w0[i] : ((i < 73728) ? w1[i - 24576] : w2[i - 73728]);
  const unsigned short h = bf16hi(v);
  hi[i] = h;
  lo[i] = bf16hi(v - bf2f(h));
}

// -------------------------------------------------------------------------
// Fused GRU layer v5 = proven v3 structure (serial group-boundary gx,
// low register pressure) + three pressure-REDUCING tweaks:
//  - z4-C first MFMA per accumulation chain (no per-step accvgpr zero-init)
//  - all-lane A-fragment reads (row l16&1; C rows 2-15 garbage, never read)
//  - lgkm-only step barriers (flush stores / prefetch stay in flight)
// Everything else identical to v3 (X staged via LDS, w_ih hi in swizzled
// LDS + lo in persistent VGPRs, gxlds parking, 8-step h flush buffers).
// -------------------------------------------------------------------------
template <int IS_L0>
__global__ __launch_bounds__(512, 2) void rec_fused(
    const float* x,                         // layer0 input (B,T,F), else unused
    const unsigned short* Xhi,              // layers>=1: prev-layer H hi (T,B,H)
    const unsigned short* Xlo,
    const unsigned short* __restrict__ Wih_hi,  // (384, KD) bf16 hi
    const unsigned short* __restrict__ Wih_lo,  // (384, KD) bf16 lo
    const float* __restrict__ w_hh, const float* __restrict__ b_ih,
    const float* __restrict__ b_hh,
    unsigned short* Hhi, unsigned short* Hlo)   // out (T,B,H)
{
  constexpr int KD   = IS_L0 ? 64 : 128;
  constexpr int NCK  = KD / 32;
  constexpr int WROW = KD * 2;              // bytes per W row in LDS
  constexpr int WGRAN = WROW / 16;          // 16B granules per W row
  constexpr int XBUF = IS_L0 ? 4096 : 8192; // bytes per X stage buffer

  __shared__ unsigned short Wlds[384 * KD];          // w_ih hi, swizzled
  __shared__ float gxlds[8 * 2 * 384];               // group gx results
  __shared__ unsigned short hbh[2][2048], hbl[2][2048]; // h history (8t x 2r x 128)
  __shared__ unsigned short hsh[2][256], hsl[2][256];   // h double buffer
  __shared__ __align__(16) unsigned char Xraw[2][XBUF]; // staged X

  const int tid  = threadIdx.x;
  const int wv   = tid >> 6, lane = tid & 63;
  const int quad = lane >> 4, l16 = lane & 15;
  const int b0   = blockIdx.x * 2;
  const int c    = wv * 16 + l16;          // owned channel (quad-0 lanes)

  const f32x4 z4 = (f32x4){0.f, 0.f, 0.f, 0.f};

  // ---- stage w_ih hi into LDS (swizzled: granule ^= row&7) ----
  {
    unsigned char* wb = (unsigned char*)Wlds;
    #pragma unroll
    for (int k = 0; k < (384 * WGRAN) / 512; ++k) {
      const int idx = k * 512 + tid;
      const int row = idx / WGRAN;
      const int gg  = idx % WGRAN;
      const uint4 v = *(const uint4*)&Wih_hi[(size_t)row * KD + gg * 8];
      *(uint4*)&wb[row * WROW + ((gg ^ (row & 7)) * 16)] = v;
    }
  }

  // ---- w_ih lo persistent fragments ----
  short8 Wl_[3][NCK];
  #pragma unroll
  for (int g_ = 0; g_ < 3; ++g_)
    #pragma unroll
    for (int ck = 0; ck < NCK; ++ck)
      Wl_[g_][ck] = *(const short8*)&Wih_lo[(size_t)(g_ * 128 + c) * KD + ck * 32 + quad * 8];

  // ---- w_hh persistent fragments (split from fp32) ----
  short8 Bh[3][4], Bl[3][4];
  #pragma unroll
  for (int g_ = 0; g_ < 3; ++g_)
    #pragma unroll
    for (int ck = 0; ck < 4; ++ck)
      split8(&w_hh[(size_t)(g_ * 128 + c) * 128 + ck * 32 + quad * 8],
             Bh[g_][ck], Bl[g_][ck]);

  float bias_r = 0.f, bias_z = 0.f, bihn = 0.f, bhhn = 0.f, h0 = 0.f, h1 = 0.f;
  if (quad == 0) {
    bias_r = b_ih[c] + b_hh[c];
    bias_z = b_ih[c + 128] + b_hh[c + 128];
    bihn = b_ih[c + 256];
    bhhn = b_hh[c + 256];
    hsh[0][c] = 0; hsh[0][128 + c] = 0;
    hsl[0][c] = 0; hsl[0][128 + c] = 0;
  }

  // ---- X staging machinery (thread-mapped, 1 uint4 per thread) ----
  const int t8 = tid & 255;
  const int sr = t8 >> 4;                  // staged row 0..15 (= 8t x 2b)
  const int sg = tid & 15;                 // 16B granule within row
  uint4 xr = {0, 0, 0, 0};

  auto load_xr = [&](int tgn) {
    if constexpr (IS_L0) {
      if (tid < 256)
        xr = *(const uint4*)&x[((size_t)(b0 + (sr & 1)) * T_LEN + tgn + (sr >> 1)) * 64 + sg * 4];
    } else {
      const unsigned short* src = (tid < 256) ? Xhi : Xlo;
      xr = *(const uint4*)&src[((size_t)(tgn + (sr >> 1)) * B_SZ + b0 + (sr & 1)) * 128 + sg * 8];
    }
  };
  auto store_xr = [&](int buf) {
    unsigned char* dstb = &Xraw[buf][0];
    const int off = sr * 256 + ((sg ^ (sr & 7)) * 16);
    if constexpr (IS_L0) {
      if (tid < 256) *(uint4*)&dstb[off] = xr;
    } else {
      *(uint4*)&dstb[(tid < 256 ? 0 : 4096) + off] = xr;
    }
  };
  auto flush_h = [&](int buf, int tp) {
    const int ft = t8 >> 5, fr = (t8 >> 4) & 1, fs = t8 & 15;
    const size_t go = ((size_t)(tp + ft) * B_SZ + b0 + fr) * 128 + fs * 8;
    const int lo_ = (ft * 2 + fr) * 128 + fs * 8;
    if (tid < 256) *(uint4*)&Hhi[go] = *(const uint4*)&hbh[buf][lo_];
    else           *(uint4*)&Hlo[go] = *(const uint4*)&hbl[buf][lo_];
  };

  // prologue: stage group 0, issue loads for group 1
  load_xr(0);
  store_xr(0);            // compiler inserts the vmcnt wait for xr
  load_xr(8);
  __syncthreads();

  for (int g = 0; g < 64; ++g) {
    // ---- flush previous group's h history (coalesced) ----
    if (g > 0) flush_h((g - 1) & 1, g * 8 - 8);

    // ---- gx for this group: A = 8 timesteps x 2 batch rows ----
    short8 Xhf[NCK], Xlf[NCK];
    {
      const unsigned char* xbuf = &Xraw[g & 1][0];
      if constexpr (IS_L0) {
        #pragma unroll
        for (int ck = 0; ck < 2; ++ck) {
          const int g0 = ck * 8 + quad * 2;
          const float4 f0 = *(const float4*)&xbuf[l16 * 256 + ((g0 ^ (l16 & 7)) * 16)];
          const float4 f1 = *(const float4*)&xbuf[l16 * 256 + (((g0 + 1) ^ (l16 & 7)) * 16)];
          split_f4pair(f0, f1, Xhf[ck], Xlf[ck]);
        }
      } else {
        #pragma unroll
        for (int ck = 0; ck < 4; ++ck) {
          const int go = ((ck * 4 + quad) ^ (l16 & 7)) * 16;
          Xhf[ck] = *(const short8*)&xbuf[l16 * 256 + go];
          Xlf[ck] = *(const short8*)&xbuf[4096 + l16 * 256 + go];
        }
      }
    }
    {
      f32x4 ax[3][2];
      const unsigned char* wb = (const unsigned char*)Wlds;
      #pragma unroll
      for (int g_ = 0; g_ < 3; ++g_) {
        ax[g_][0] = z4;
        ax[g_][1] = z4;
      }
      #pragma unroll
      for (int ck = 0; ck < NCK; ++ck) {
        const int p = (NCK == 4) ? (ck >> 1) : ck;
        #pragma unroll
        for (int g_ = 0; g_ < 3; ++g_) {
          const int n = g_ * 128 + c;
          const short8 wh = *(const short8*)&wb[n * WROW + (((ck * 4 + quad) ^ (n & 7)) * 16)];
          ax[g_][p] = __builtin_amdgcn_mfma_f32_16x16x32_bf16(Xhf[ck], wh, ax[g_][p], 0, 0, 0);
          ax[g_][p] = __builtin_amdgcn_mfma_f32_16x16x32_bf16(Xhf[ck], Wl_[g_][ck], ax[g_][p], 0, 0, 0);
          ax[g_][p] = __builtin_amdgcn_mfma_f32_16x16x32_bf16(Xlf[ck], wh, ax[g_][p], 0, 0, 0);
        }
      }
      // park gx in LDS: D row rr=quad*4+reg -> (tt = quad*2+(reg>>1), r = reg&1)
      #pragma unroll
      for (int g_ = 0; g_ < 3; ++g_)
        #pragma unroll
        for (int reg = 0; reg < 4; ++reg) {
          const int tt_ = quad * 2 + (reg >> 1);
          const int r_  = reg & 1;
          gxlds[(tt_ * 2 + r_) * 384 + g_ * 128 + c] = ax[g_][0][reg] + ax[g_][1][reg];
        }
    }
    step_barrier();   // gxlds + staged X visible; hbuf flushed reads done

    // ---- 8 recurrence steps: pure LDS + MFMA + VALU ----
    #pragma unroll
    for (int tt = 0; tt < 8; ++tt) {
      // gate inputs from gxlds (issued early, hidden under MFMAs)
      float gr0 = 0.f, gz0 = 0.f, gn0v = 0.f, gr1 = 0.f, gz1 = 0.f, gn1v = 0.f;
      if (quad == 0) {
        const float* gp = &gxlds[tt * 768 + c];
        gr0 = gp[0];   gz0 = gp[128]; gn0v = gp[256];
        gr1 = gp[384]; gz1 = gp[512]; gn1v = gp[640];
      }

      // h A-fragments: ALL lanes read row l16&1 (C rows >=2 unused garbage)
      short8 Ahf[4], Alf[4];
      #pragma unroll
      for (int ck = 0; ck < 4; ++ck) {
        const int ad = (l16 & 1) * 128 + ck * 32 + quad * 8;
        Ahf[ck] = *(const short8*)&hsh[tt & 1][ad];
        Alf[ck] = *(const short8*)&hsl[tt & 1][ad];
      }

      // gh MFMAs: 6 chains of 6, first op takes C=0 (no accvgpr zero-init)
      f32x4 acc[3][2];
      #pragma unroll
      for (int g_ = 0; g_ < 3; ++g_) {
        #pragma unroll
        for (int p = 0; p < 2; ++p) {
          const int k0 = p * 2;
          acc[g_][p] = __builtin_amdgcn_mfma_f32_16x16x32_bf16(Ahf[k0], Bh[g_][k0], z4, 0, 0, 0);
          acc[g_][p] = __builtin_amdgcn_mfma_f32_16x16x32_bf16(Ahf[k0], Bl[g_][k0], acc[g_][p], 0, 0, 0);
          acc[g_][p] = __builtin_amdgcn_mfma_f32_16x16x32_bf16(Alf[k0], Bh[g_][k0], acc[g_][p], 0, 0, 0);
          acc[g_][p] = __builtin_amdgcn_mfma_f32_16x16x32_bf16(Ahf[k0 + 1], Bh[g_][k0 + 1], acc[g_][p], 0, 0, 0);
          acc[g_][p] = __builtin_amdgcn_mfma_f32_16x16x32_bf16(Ahf[k0 + 1], Bl[g_][k0 + 1], acc[g_][p], 0, 0, 0);
          acc[g_][p] = __builtin_amdgcn_mfma_f32_16x16x32_bf16(Alf[k0 + 1], Bh[g_][k0 + 1], acc[g_][p], 0, 0, 0);
        }
      }

      if (quad == 0) {
        const float ghr0 = acc[0][0][0] + acc[0][1][0];
        const float ghr1 = acc[0][0][1] + acc[0][1][1];
        const float ghz0 = acc[1][0][0] + acc[1][1][0];
        const float ghz1 = acc[1][0][1] + acc[1][1][1];
        const float ghn0 = acc[2][0][0] + acc[2][1][0];
        const float ghn1 = acc[2][0][1] + acc[2][1][1];
        const float r0 = fsig(gr0 + ghr0 + bias_r);
        const float z0 = fsig(gz0 + ghz0 + bias_z);
        const float nv0 = ftanh(gn0v + bihn + r0 * (ghn0 + bhhn));
        const float hn0 = (1.0f - z0) * nv0 + z0 * h0;
        const float r1 = fsig(gr1 + ghr1 + bias_r);
        const float z1 = fsig(gz1 + ghz1 + bias_z);
        const float nv1 = ftanh(gn1v + bihn + r1 * (ghn1 + bhhn));
        const float hn1 = (1.0f - z1) * nv1 + z1 * h1;
        h0 = hn0; h1 = hn1;
        const int nb = (tt + 1) & 1;
        const unsigned short hh0 = bf16hi(hn0), hh1 = bf16hi(hn1);
        const unsigned short hl0 = bf16hi(hn0 - bf2f(hh0));
        const unsigned short hl1 = bf16hi(hn1 - bf2f(hh1));
        hsh[nb][c] = hh0;       hsh[nb][128 + c] = hh1;
        hsl[nb][c] = hl0;       hsl[nb][128 + c] = hl1;
        const int hb = (tt * 2) * 128 + c;
        hbh[g & 1][hb] = hh0;       hbh[g & 1][hb + 128] = hh1;
        hbl[g & 1][hb] = hl0;       hbl[g & 1][hb + 128] = hl1;
      }

      // step 7: commit staged X for next group, then issue loads for g+2
      if (tt == 7 && g + 1 < 64) {
        store_xr((g + 1) & 1);       // data-dep vmcnt wait on xr only
        if (g + 2 < 64) load_xr((g + 2) * 8);
      }
      step_barrier();
    }
  }
  // final flush (group 63, 8-step buffer: timesteps 504..511)
  flush_h(1, 504);
}

// -------------------------------------------------------------------------
// keys = H @ aWk^T + abk, split-bf16 MFMA. Output Kbt in (B, T, H) order
// (bf16 RNE) so each decoder block reads a CONTIGUOUS 128 KB slice.
// -------------------------------------------------------------------------
__global__ __launch_bounds__(256) void keys_gemm(
    const unsigned short* __restrict__ Ahi, const unsigned short* __restrict__ Alo,
    const float* __restrict__ aWk, const float* __restrict__ abk,
    unsigned short* __restrict__ Kbt)
{
  __shared__ unsigned short Ah[64 * 40], Al[64 * 40];
  __shared__ unsigned short Bh[128 * 136], Bl[128 * 136];
  const int tid  = threadIdx.x;
  const int wave = tid >> 6, lane = tid & 63;
  const int quad = lane >> 4, l16 = lane & 15;
  const size_t m0 = (size_t)blockIdx.x * 64;

  for (int i = tid; i < 16384; i += 256) {
    const float v = aWk[i];
    const unsigned short h = bf16hi(v);
    const int r = i >> 7, k = i & 127;
    Bh[r * 136 + k] = h;
    Bl[r * 136 + k] = bf16hi(v - bf2f(h));
  }

  f32x4 acc[8];
  #pragma unroll
  for (int i = 0; i < 8; ++i) acc[i] = (f32x4){0.f, 0.f, 0.f, 0.f};
  float bias[8];
  #pragma unroll
  for (int nt = 0; nt < 8; ++nt) bias[nt] = abk[nt * 16 + l16];

  const int r = tid >> 2, c8 = (tid & 3) * 8;
  for (int kc = 0; kc < 128; kc += 32) {
    __syncthreads();
    const size_t src = (m0 + r) * 128 + kc + c8;
    *(uint4*)&Ah[r * 40 + c8] = *(const uint4*)&Ahi[src];
    *(uint4*)&Al[r * 40 + c8] = *(const uint4*)&Alo[src];
    __syncthreads();
    const short8 a_hi = *(const short8*)&Ah[(wave * 16 + l16) * 40 + quad * 8];
    const short8 a_lo = *(const short8*)&Al[(wave * 16 + l16) * 40 + quad * 8];
    #pragma unroll
    for (int nt = 0; nt < 8; ++nt) {
      const short8 b_hi = *(const short8*)&Bh[(nt * 16 + l16) * 136 + kc + quad * 8];
      const short8 b_lo = *(const short8*)&Bl[(nt * 16 + l16) * 136 + kc + quad * 8];
      acc[nt] = __builtin_amdgcn_mfma_f32_16x16x32_bf16(a_hi, b_hi, acc[nt], 0, 0, 0);
      acc[nt] = __builtin_amdgcn_mfma_f32_16x16x32_bf16(a_hi, b_lo, acc[nt], 0, 0, 0);
      acc[nt] = __builtin_amdgcn_mfma_f32_16x16x32_bf16(a_lo, b_hi, acc[nt], 0, 0, 0);
    }
  }
  #pragma unroll
  for (int nt = 0; nt < 8; ++nt) {
    #pragma unroll
    for (int reg = 0; reg < 4; ++reg) {
      const size_t m = m0 + wave * 16 + quad * 4 + reg;   // m = t*B + b
      const size_t b = m & 511, t = m >> 9;
      const int n = nt * 16 + l16;
      Kbt[(b * T_LEN + t) * 128 + n] = bf16hi(acc[nt][reg] + bias[nt]);
    }
  }
}

// -------------------------------------------------------------------------
// Stash last hidden state h_T (fp32) before Hlo is recycled as H_bt.
// -------------------------------------------------------------------------
__global__ __launch_bounds__(512) void save_lasth(
    const unsigned short* __restrict__ Hhi, const unsigned short* __restrict__ Hlo,
    float* __restrict__ lastH)
{
  const int i = blockIdx.x * 512 + threadIdx.x;   // 65536 = 512 b x 128 c
  const size_t src = ((size_t)(T_LEN - 1) * B_SZ) * 128 + i;
  lastH[i] = bf2f(Hhi[src]) + bf2f(Hlo[src]);
}

// -------------------------------------------------------------------------
// Transpose Hhi (T,B,H) -> H_bt (B,T,H) so decoder ctx reads contiguous.
// Grid 4096: blk>>3 = b, blk&7 = 64-timestep group. 256 thr, 4 uint4 each.
// -------------------------------------------------------------------------
__global__ __launch_bounds__(256) void transpose_h(
    const unsigned short* __restrict__ Hhi, unsigned short* __restrict__ Hbt)
{
  const int b  = blockIdx.x >> 3;
  const int tg = blockIdx.x & 7;
  #pragma unroll
  for (int j = 0; j < 4; ++j) {
    const int id = threadIdx.x * 4 + j;
    const int tl = id >> 4;            // 0..63
    const int ch = (id & 15) * 8;      // 16-B chunk
    const int t  = tg * 64 + tl;
    const uint4 v = *(const uint4*)&Hhi[((size_t)t * B_SZ + b) * 128 + ch];
    *(uint4*)&Hbt[((size_t)b * T_LEN + t) * 128 + ch] = v;
  }
}

// -------------------------------------------------------------------------
// Decoder v5: one block per batch row; K and H in (B,T,H) order -> each
// block's 2x128KB working set is L2/L3-resident across the 8 steps.
// -------------------------------------------------------------------------
__global__ __launch_bounds__(512) void decoder(
    const unsigned short* __restrict__ Hbt,
    const unsigned short* __restrict__ Kbt,
    const float* __restrict__ lastH,
    const float* __restrict__ aWq, const float* __restrict__ abq,
    const float* __restrict__ av,
    const float* __restrict__ dwih, const float* __restrict__ dwhh,
    const float* __restrict__ dbih, const float* __restrict__ dbhh,
    const float* __restrict__ lng, const float* __restrict__ lnb,
    const float* __restrict__ w1, const float* __restrict__ b1,
    const float* __restrict__ w2, const float* __restrict__ b2,
    float* __restrict__ out)
{
  __shared__ float h_s[128], q_s[128], av_s[128], s_s[512], w_s[512];
  __shared__ float part[8][128], u_s[256], gx_s[384], gh_s[384], y_s[128];
  __shared__ float red[16];
  const int b = blockIdx.x, tid = threadIdx.x;
  const int wave = tid >> 6, lane = tid & 63;
  const int tslot = lane >> 4, ks = lane & 15;

  if (tid < 128) {
    h_s[tid] = lastH[(size_t)b * 128 + tid];
    av_s[tid] = av[tid];
  }
  __syncthreads();

  for (int step = 0; step < NSTEP; ++step) {
    if (tid < 128) {
      float acc = abq[tid];
      const float* wr = &aWq[(size_t)tid * 128];
      #pragma unroll 8
      for (int k4 = 0; k4 < 32; ++k4) {
        const float4 hv = *(const float4*)&h_s[k4 * 4];
        const float4 wv = *(const float4*)&wr[k4 * 4];
        acc += hv.x * wv.x + hv.y * wv.y + hv.z * wv.z + hv.w * wv.w;
      }
      q_s[tid] = acc;
    }
    __syncthreads();
    #pragma unroll 2
    for (int it = 0; it < 16; ++it) {
      const int t = it * 32 + wave * 4 + tslot;
      const size_t kb = ((size_t)b * T_LEN + t) * 128 + ks * 8;
      const uint4 uh = *(const uint4*)&Kbt[kb];
      const float4 q0 = *(const float4*)&q_s[ks * 8];
      const float4 q1 = *(const float4*)&q_s[ks * 8 + 4];
      const float4 a0 = *(const float4*)&av_s[ks * 8];
      const float4 a1 = *(const float4*)&av_s[ks * 8 + 4];
      float acc = ftanh(bflo(uh.x) + q0.x) * a0.x + ftanh(bfhi(uh.x) + q0.y) * a0.y
                + ftanh(bflo(uh.y) + q0.z) * a0.z + ftanh(bfhi(uh.y) + q0.w) * a0.w
                + ftanh(bflo(uh.z) + q1.x) * a1.x + ftanh(bfhi(uh.z) + q1.y) * a1.y
                + ftanh(bflo(uh.w) + q1.z) * a1.z + ftanh(bfhi(uh.w) + q1.w) * a1.w;
      acc = row_sum16(acc);
      if (ks == 0) s_s[t] = acc;
    }
    __syncthreads();
    {
      const float sv = s_s[tid];
      float mx = sv;
      #pragma unroll
      for (int o = 32; o; o >>= 1) mx = fmaxf(mx, __shfl_xor(mx, o, 64));
      if (lane == 0) red[wave] = mx;
      __syncthreads();
      mx = red[0];
      #pragma unroll
      for (int i = 1; i < 8; ++i) mx = fmaxf(mx, red[i]);
      const float e = __expf(sv - mx);
      float sm = e;
      #pragma unroll
      for (int o = 32; o; o >>= 1) sm += __shfl_xor(sm, o, 64);
      if (lane == 0) red[8 + wave] = sm;
      __syncthreads();
      float tot = red[8];
      #pragma unroll
      for (int i = 1; i < 8; ++i) tot += red[8 + i];
      w_s[tid] = e / tot;
    }
    __syncthreads();
    {
      const int th = tid >> 6;
      const int c2 = (tid & 63) * 2;
      float acc0 = 0.0f, acc1 = 0.0f;
      #pragma unroll 4
      for (int q = 0; q < 64; ++q) {
        const int t = th * 64 + q;
        const unsigned u = *(const unsigned*)&Hbt[((size_t)b * T_LEN + t) * 128 + c2];
        const float wt = w_s[t];
        acc0 += wt * bflo(u);
        acc1 += wt * bfhi(u);
      }
      part[th][c2] = acc0;
      part[th][c2 + 1] = acc1;
    }
    __syncthreads();
    if (tid < 128) {
      float s = part[0][tid];
      #pragma unroll
      for (int i = 1; i < 8; ++i) s += part[i][tid];
      u_s[tid] = s;
      u_s[128 + tid] = h_s[tid];
    }
    __syncthreads();
    if (tid < 384) {
      const int j = tid;
      float gxv = dbih[j], ghv = dbhh[j];
      const float* wxr = &dwih[(size_t)j * 256];
      const float* whr = &dwhh[(size_t)j * 128];
      #pragma unroll 8
      for (int k4 = 0; k4 < 64; ++k4) {
        const float4 uv = *(const float4*)&u_s[k4 * 4];
        const float4 wv = *(const float4*)&wxr[k4 * 4];
        gxv += uv.x * wv.x + uv.y * wv.y + uv.z * wv.z + uv.w * wv.w;
      }
      #pragma unroll 8
      for (int k4 = 0; k4 < 32; ++k4) {
        const float4 hv = *(const float4*)&h_s[k4 * 4];
        const float4 wv = *(const float4*)&whr[k4 * 4];
        ghv += hv.x * wv.x + hv.y * wv.y + hv.z * wv.z + hv.w * wv.w;
      }
      gx_s[j] = gxv; gh_s[j] = ghv;
    }
    __syncthreads();
    if (tid < 128) {
      const float r = fsig(gx_s[tid] + gh_s[tid]);
      const float z = fsig(gx_s[128 + tid] + gh_s[128 + tid]);
      const float n = ftanh(gx_s[256 + tid] + r * gh_s[256 + tid]);
      const float hn = (1.0f - z) * n + z * h_s[tid];
      h_s[tid] = hn;
      float s1 = hn, s2 = hn * hn;
      #pragma unroll
      for (int o = 32; o; o >>= 1) { s1 += __shfl_xor(s1, o, 64); s2 += __shfl_xor(s2, o, 64); }
      if ((tid & 63) == 0) { red[tid >> 6] = s1; red[4 + (tid >> 6)] = s2; }
    }
    __syncthreads();
    if (tid < 128) {
      const float hn  = h_s[tid];
      const float mu  = (red[0] + red[1]) * (1.0f / 128.0f);
      const float var = (red[4] + red[5]) * (1.0f / 128.0f) - mu * mu;
      y_s[tid] = (hn - mu) / sqrtf(var + 1e-5f) * lng[tid] + lnb[tid];
    }
    __syncthreads();
    if (tid < 64) {
      float acc = b1[tid];
      const float* wr = &w1[(size_t)tid * 128];
      #pragma unroll 8
      for (int k4 = 0; k4 < 32; ++k4) {
        const float4 yv = *(const float4*)&y_s[k4 * 4];
        const float4 wv = *(const float4*)&wr[k4 * 4];
        acc += yv.x * wv.x + yv.y * wv.y + yv.z * wv.z + yv.w * wv.w;
      }
      acc = fmaxf(acc, 0.0f);
      float v = acc * w2[tid];
      #pragma unroll
      for (int o = 32; o; o >>= 1) v += __shfl_xor(v, o, 64);
      if (tid == 0) out[(size_t)b * NSTEP + step] = v + b2[0];
    }
    __syncthreads();
  }
}

// -------------------------------------------------------------------------
extern "C" void kernel_launch(void* const* d_in, const int* in_sizes, int n_in,
                              void* d_out, int out_size, void* d_ws, size_t ws_size,
                              hipStream_t stream)
{
  (void)in_sizes; (void)n_in; (void)out_size; (void)ws_size;
  const float* x    = (const float*)d_in[0];
  const float* ewih[3] = {(const float*)d_in[1], (const float*)d_in[5], (const float*)d_in[9]};
  const float* ewhh[3] = {(const float*)d_in[2], (const float*)d_in[6], (const float*)d_in[10]};
  const float* ebih[3] = {(const float*)d_in[3], (const float*)d_in[7], (const float*)d_in[11]};
  const float* ebhh[3] = {(const float*)d_in[4], (const float*)d_in[8], (const float*)d_in[12]};
  const float* aWq  = (const float*)d_in[13];
  const float* abq  = (const float*)d_in[14];
  const float* aWk  = (const float*)d_in[15];
  const float* abk  = (const float*)d_in[16];
  const float* av   = (const float*)d_in[17];
  const float* dwih = (const float*)d_in[18];
  const float* dwhh = (const float*)d_in[19];
  const float* dbih = (const float*)d_in[20];
  const float* dbhh = (const float*)d_in[21];
  const float* lng  = (const float*)d_in[22];
  const float* lnb  = (const float*)d_in[23];
  const float* w1   = (const float*)d_in[24];
  const float* b1   = (const float*)d_in[25];
  const float* w2   = (const float*)d_in[26];
  const float* b2   = (const float*)d_in[27];

  const size_t HN = (size_t)T_LEN * B_SZ * H_DIM;               // 33,554,432 elems
  unsigned short* Hhi = (unsigned short*)d_ws;                  // 64 MiB (T,B,H)
  unsigned short* Hlo = Hhi + HN;                               // 64 MiB (later: H_bt)
  float* regionC = (float*)(Hlo + HN);                          // 128 MiB
  unsigned short* Whi = (unsigned short*)(regionC + 25165824 + 65536);
  unsigned short* Wlo = Whi + 122880;
  unsigned short* Kbt = (unsigned short*)regionC;               // decode: 64 MiB
  float* lastH = regionC + 16777216;                            // +64 MiB, 256 KiB

  prep_split<<<dim3(480), dim3(256), 0, stream>>>(ewih[0], ewih[1], ewih[2], Whi, Wlo);

  rec_fused<1><<<dim3(256), dim3(512), 0, stream>>>(
      x, nullptr, nullptr, Whi, Wlo,
      ewhh[0], ebih[0], ebhh[0], Hhi, Hlo);
  rec_fused<0><<<dim3(256), dim3(512), 0, stream>>>(
      nullptr, Hhi, Hlo, Whi + 24576, Wlo + 24576,
      ewhh[1], ebih[1], ebhh[1], Hhi, Hlo);
  rec_fused<0><<<dim3(256), dim3(512), 0, stream>>>(
      nullptr, Hhi, Hlo, Whi + 73728, Wlo + 73728,
      ewhh[2], ebih[2], ebhh[2], Hhi, Hlo);

  keys_gemm<<<dim3(4096), dim3(256), 0, stream>>>(Hhi, Hlo, aWk, abk, Kbt);
  save_lasth<<<dim3(128), dim3(512), 0, stream>>>(Hhi, Hlo, lastH);
  // Hlo is dead after keys_gemm + save_lasth: recycle it as H_bt (B,T,H)
  transpose_h<<<dim3(4096), dim3(256), 0, stream>>>(Hhi, Hlo);
  decoder<<<dim3(512), dim3(512), 0, stream>>>(
      Hlo, Kbt, lastH, aWq, abq, av, dwih, dwhh, dbih, dbhh,
      lng, lnb, w1, b1, w2, b2, (float*)d_out);
}

// Round 7
// 2389.482 us; speedup vs baseline: 1.3085x; 1.1006x over previous
//
#include <hip/hip_runtime.h>
#include <hip/hip_bf16.h>
#include <cstdint>
#include <cstddef>

#define T_LEN 512
#define B_SZ  512
#define F_IN  64
#define H_DIM 128
#define NSTEP 8

typedef __attribute__((ext_vector_type(8))) short short8;
typedef __attribute__((ext_vector_type(4))) float f32x4;

__device__ __forceinline__ float fsig(float x) { return 1.0f / (1.0f + __expf(-x)); }
__device__ __forceinline__ float ftanh(float x) {
  float e = __expf(-2.0f * fabsf(x));
  float t = (1.0f - e) / (1.0f + e);
  return copysignf(t, x);
}
__device__ __forceinline__ unsigned short bf16hi(float x) {
  __hip_bfloat16 h = __float2bfloat16(x);
  return *(unsigned short*)&h;
}
__device__ __forceinline__ float bf2f(unsigned short u) {
  return __uint_as_float(((unsigned)u) << 16);
}
__device__ __forceinline__ float bflo(unsigned u) { return __uint_as_float(u << 16); }
__device__ __forceinline__ float bfhi(unsigned u) { return __uint_as_float(u & 0xffff0000u); }

// lgkm-only barrier: LDS consistency without draining vmcnt (flush stores and
// prefetch loads stay in flight across steps; loads are consumed via the
// compiler's data-dependent vmcnt waits).
__device__ __forceinline__ void step_barrier() {
  asm volatile("s_waitcnt lgkmcnt(0)" ::: "memory");
  __builtin_amdgcn_s_barrier();
  asm volatile("" ::: "memory");
}

// DPP cross-lane add within 16-lane rows (decoder scores)
template <int CTRL>
__device__ __forceinline__ float dpp_add(float v) {
  int p = __builtin_amdgcn_update_dpp(0, __float_as_int(v), CTRL, 0xF, 0xF, true);
  return v + __int_as_float(p);
}
__device__ __forceinline__ float row_sum16(float v) {
  v = dpp_add<0xB1>(v);
  v = dpp_add<0x4E>(v);
  v = dpp_add<0x124>(v);
  v = dpp_add<0x128>(v);
  return v;
}

// split 8 consecutive fp32 into bf16 hi/lo short8 fragments
__device__ __forceinline__ void split8(const float* p, short8& hi, short8& lo) {
  #pragma unroll
  for (int i = 0; i < 8; ++i) {
    const float v = p[i];
    const unsigned short h = bf16hi(v);
    hi[i] = (short)h;
    lo[i] = (short)bf16hi(v - bf2f(h));
  }
}

// split two adjacent float4 (8 fp32) into bf16 hi/lo short8 fragments
__device__ __forceinline__ void split_f4pair(const float4 a, const float4 b,
                                             short8& hi, short8& lo) {
  const float v[8] = {a.x, a.y, a.z, a.w, b.x, b.y, b.z, b.w};
  #pragma unroll
  for (int j = 0; j < 8; ++j) {
    const unsigned short h = bf16hi(v[j]);
    hi[j] = (short)h;
    lo[j] = (short)bf16hi(v[j] - bf2f(h));
  }
}

// -------------------------------------------------------------------------
// Split the 3 encoder w_ih matrices into bf16 hi/lo pairs (one-time prep).
// -------------------------------------------------------------------------
__global__ __launch_bounds__(256) void prep_split(
    const float* __restrict__ w0, const float* __restrict__ w1,
    const float* __restrict__ w2,
    unsigned short* __restrict__ hi, unsigned short* __restrict__ lo)
{
  const int i = blockIdx.x * 256 + threadIdx.x;
  if (i >= 122880) return;
  float v = (i < 24576) ? w0[i] : ((i < 73728) ? w1[i - 24576] : w2[i - 73728]);
  const unsigned short h = bf16hi(v);
  hi[i] = h;
  lo[i] = bf16hi(v - bf2f(h));
}

// -------------------------------------------------------------------------
// Fused GRU layer v6 = v5 structure + PACKED hi/lo A-tile for the gh MFMA:
// A rows 0-3 = {h0_hi, h1_hi, h0_lo, h1_lo} (all lanes read row l16&3).
// One MFMA pair (xB_hi, xB_lo) then yields ALL split products in fp32:
//   C row0 = h0_hi*B, row2 = h0_lo*B  ->  gh_r0 = reg0 + reg2 (per partial).
// gh MFMAs/step: 36 -> 24 (and now includes the lo*lo term: MORE accurate);
// A-fragment ds_reads: 8 -> 4. Wlds swizzle widened to the full granule
// mask (&15 for KD=128) to cut the boundary W-read conflict 8->4-way.
// Everything else identical to v5.
// -------------------------------------------------------------------------
template <int IS_L0>
__global__ __launch_bounds__(512, 2) void rec_fused(
    const float* x,                         // layer0 input (B,T,F), else unused
    const unsigned short* Xhi,              // layers>=1: prev-layer H hi (T,B,H)
    const unsigned short* Xlo,
    const unsigned short* __restrict__ Wih_hi,  // (384, KD) bf16 hi
    const unsigned short* __restrict__ Wih_lo,  // (384, KD) bf16 lo
    const float* __restrict__ w_hh, const float* __restrict__ b_ih,
    const float* __restrict__ b_hh,
    unsigned short* Hhi, unsigned short* Hlo)   // out (T,B,H)
{
  constexpr int KD   = IS_L0 ? 64 : 128;
  constexpr int NCK  = KD / 32;
  constexpr int WROW = KD * 2;              // bytes per W row in LDS
  constexpr int WGRAN = WROW / 16;          // 16B granules per W row
  constexpr int XBUF = IS_L0 ? 4096 : 8192; // bytes per X stage buffer

  __shared__ unsigned short Wlds[384 * KD];          // w_ih hi, swizzled
  __shared__ float gxlds[8 * 2 * 384];               // group gx results
  __shared__ unsigned short hbh[2][2048], hbl[2][2048]; // h history (8t x 2r x 128)
  __shared__ unsigned short hs[2][512];              // packed h: rows {h0hi,h1hi,h0lo,h1lo}
  __shared__ __align__(16) unsigned char Xraw[2][XBUF]; // staged X

  const int tid  = threadIdx.x;
  const int wv   = tid >> 6, lane = tid & 63;
  const int quad = lane >> 4, l16 = lane & 15;
  const int b0   = blockIdx.x * 2;
  const int c    = wv * 16 + l16;          // owned channel (quad-0 lanes)

  const f32x4 z4 = (f32x4){0.f, 0.f, 0.f, 0.f};

  // ---- stage w_ih hi into LDS (swizzled: granule ^= row & (WGRAN-1)) ----
  {
    unsigned char* wb = (unsigned char*)Wlds;
    #pragma unroll
    for (int k = 0; k < (384 * WGRAN) / 512; ++k) {
      const int idx = k * 512 + tid;
      const int row = idx / WGRAN;
      const int gg  = idx % WGRAN;
      const uint4 v = *(const uint4*)&Wih_hi[(size_t)row * KD + gg * 8];
      *(uint4*)&wb[row * WROW + ((gg ^ (row & (WGRAN - 1))) * 16)] = v;
    }
  }

  // ---- w_ih lo persistent fragments ----
  short8 Wl_[3][NCK];
  #pragma unroll
  for (int g_ = 0; g_ < 3; ++g_)
    #pragma unroll
    for (int ck = 0; ck < NCK; ++ck)
      Wl_[g_][ck] = *(const short8*)&Wih_lo[(size_t)(g_ * 128 + c) * KD + ck * 32 + quad * 8];

  // ---- w_hh persistent fragments (split from fp32) ----
  short8 Bh[3][4], Bl[3][4];
  #pragma unroll
  for (int g_ = 0; g_ < 3; ++g_)
    #pragma unroll
    for (int ck = 0; ck < 4; ++ck)
      split8(&w_hh[(size_t)(g_ * 128 + c) * 128 + ck * 32 + quad * 8],
             Bh[g_][ck], Bl[g_][ck]);

  float bias_r = 0.f, bias_z = 0.f, bihn = 0.f, bhhn = 0.f, h0 = 0.f, h1 = 0.f;
  if (quad == 0) {
    bias_r = b_ih[c] + b_hh[c];
    bias_z = b_ih[c + 128] + b_hh[c + 128];
    bihn = b_ih[c + 256];
    bhhn = b_hh[c + 256];
    hs[0][c] = 0; hs[0][128 + c] = 0;      // h0_hi, h1_hi
    hs[0][256 + c] = 0; hs[0][384 + c] = 0; // h0_lo, h1_lo
  }

  // ---- X staging machinery (thread-mapped, 1 uint4 per thread) ----
  const int t8 = tid & 255;
  const int sr = t8 >> 4;                  // staged row 0..15 (= 8t x 2b)
  const int sg = tid & 15;                 // 16B granule within row
  uint4 xr = {0, 0, 0, 0};

  auto load_xr = [&](int tgn) {
    if constexpr (IS_L0) {
      if (tid < 256)
        xr = *(const uint4*)&x[((size_t)(b0 + (sr & 1)) * T_LEN + tgn + (sr >> 1)) * 64 + sg * 4];
    } else {
      const unsigned short* src = (tid < 256) ? Xhi : Xlo;
      xr = *(const uint4*)&src[((size_t)(tgn + (sr >> 1)) * B_SZ + b0 + (sr & 1)) * 128 + sg * 8];
    }
  };
  auto store_xr = [&](int buf) {
    unsigned char* dstb = &Xraw[buf][0];
    const int off = sr * 256 + ((sg ^ (sr & 7)) * 16);
    if constexpr (IS_L0) {
      if (tid < 256) *(uint4*)&dstb[off] = xr;
    } else {
      *(uint4*)&dstb[(tid < 256 ? 0 : 4096) + off] = xr;
    }
  };
  auto flush_h = [&](int buf, int tp) {
    const int ft = t8 >> 5, fr = (t8 >> 4) & 1, fs = t8 & 15;
    const size_t go = ((size_t)(tp + ft) * B_SZ + b0 + fr) * 128 + fs * 8;
    const int lo_ = (ft * 2 + fr) * 128 + fs * 8;
    if (tid < 256) *(uint4*)&Hhi[go] = *(const uint4*)&hbh[buf][lo_];
    else           *(uint4*)&Hlo[go] = *(const uint4*)&hbl[buf][lo_];
  };

  // prologue: stage group 0, issue loads for group 1
  load_xr(0);
  store_xr(0);            // compiler inserts the vmcnt wait for xr
  load_xr(8);
  __syncthreads();

  for (int g = 0; g < 64; ++g) {
    // ---- flush previous group's h history (coalesced) ----
    if (g > 0) flush_h((g - 1) & 1, g * 8 - 8);

    // ---- gx for this group: A = 8 timesteps x 2 batch rows ----
    short8 Xhf[NCK], Xlf[NCK];
    {
      const unsigned char* xbuf = &Xraw[g & 1][0];
      if constexpr (IS_L0) {
        #pragma unroll
        for (int ck = 0; ck < 2; ++ck) {
          const int g0 = ck * 8 + quad * 2;
          const float4 f0 = *(const float4*)&xbuf[l16 * 256 + ((g0 ^ (l16 & 7)) * 16)];
          const float4 f1 = *(const float4*)&xbuf[l16 * 256 + (((g0 + 1) ^ (l16 & 7)) * 16)];
          split_f4pair(f0, f1, Xhf[ck], Xlf[ck]);
        }
      } else {
        #pragma unroll
        for (int ck = 0; ck < 4; ++ck) {
          const int go = ((ck * 4 + quad) ^ (l16 & 7)) * 16;
          Xhf[ck] = *(const short8*)&xbuf[l16 * 256 + go];
          Xlf[ck] = *(const short8*)&xbuf[4096 + l16 * 256 + go];
        }
      }
    }
    {
      f32x4 ax[3][2];
      const unsigned char* wb = (const unsigned char*)Wlds;
      #pragma unroll
      for (int g_ = 0; g_ < 3; ++g_) {
        ax[g_][0] = z4;
        ax[g_][1] = z4;
      }
      #pragma unroll
      for (int ck = 0; ck < NCK; ++ck) {
        const int p = (NCK == 4) ? (ck >> 1) : ck;
        #pragma unroll
        for (int g_ = 0; g_ < 3; ++g_) {
          const int n = g_ * 128 + c;
          const short8 wh = *(const short8*)&wb[n * WROW + (((ck * 4 + quad) ^ (n & (WGRAN - 1))) * 16)];
          ax[g_][p] = __builtin_amdgcn_mfma_f32_16x16x32_bf16(Xhf[ck], wh, ax[g_][p], 0, 0, 0);
          ax[g_][p] = __builtin_amdgcn_mfma_f32_16x16x32_bf16(Xhf[ck], Wl_[g_][ck], ax[g_][p], 0, 0, 0);
          ax[g_][p] = __builtin_amdgcn_mfma_f32_16x16x32_bf16(Xlf[ck], wh, ax[g_][p], 0, 0, 0);
        }
      }
      // park gx in LDS: D row rr=quad*4+reg -> (tt = quad*2+(reg>>1), r = reg&1)
      #pragma unroll
      for (int g_ = 0; g_ < 3; ++g_)
        #pragma unroll
        for (int reg = 0; reg < 4; ++reg) {
          const int tt_ = quad * 2 + (reg >> 1);
          const int r_  = reg & 1;
          gxlds[(tt_ * 2 + r_) * 384 + g_ * 128 + c] = ax[g_][0][reg] + ax[g_][1][reg];
        }
    }
    step_barrier();   // gxlds + staged X visible; hbuf flushed reads done

    // ---- 8 recurrence steps: pure LDS + MFMA + VALU ----
    #pragma unroll
    for (int tt = 0; tt < 8; ++tt) {
      // gate inputs from gxlds (issued early, hidden under MFMAs)
      float gr0 = 0.f, gz0 = 0.f, gn0v = 0.f, gr1 = 0.f, gz1 = 0.f, gn1v = 0.f;
      if (quad == 0) {
        const float* gp = &gxlds[tt * 768 + c];
        gr0 = gp[0];   gz0 = gp[128]; gn0v = gp[256];
        gr1 = gp[384]; gz1 = gp[512]; gn1v = gp[640];
      }

      // packed h A-fragments: lane row = l16&3 (C rows 4-15 duplicate, unread)
      short8 Af[4];
      #pragma unroll
      for (int ck = 0; ck < 4; ++ck) {
        const int ad = (l16 & 3) * 128 + ck * 32 + quad * 8;
        Af[ck] = *(const short8*)&hs[tt & 1][ad];
      }

      // gh MFMAs: 3 gates x 2 partials x 4 (ck pair x {B_hi,B_lo}); packed A
      // gives hi*B in C rows 0-1 and lo*B in rows 2-3 simultaneously.
      f32x4 acc[3][2];
      #pragma unroll
      for (int g_ = 0; g_ < 3; ++g_) {
        #pragma unroll
        for (int p = 0; p < 2; ++p) {
          const int k0 = p * 2;
          acc[g_][p] = __builtin_amdgcn_mfma_f32_16x16x32_bf16(Af[k0], Bh[g_][k0], z4, 0, 0, 0);
          acc[g_][p] = __builtin_amdgcn_mfma_f32_16x16x32_bf16(Af[k0], Bl[g_][k0], acc[g_][p], 0, 0, 0);
          acc[g_][p] = __builtin_amdgcn_mfma_f32_16x16x32_bf16(Af[k0 + 1], Bh[g_][k0 + 1], acc[g_][p], 0, 0, 0);
          acc[g_][p] = __builtin_amdgcn_mfma_f32_16x16x32_bf16(Af[k0 + 1], Bl[g_][k0 + 1], acc[g_][p], 0, 0, 0);
        }
      }

      if (quad == 0) {
        // row0(h0_hi*B) + row2(h0_lo*B) = full-precision h0*B; same for h1
        const float ghr0 = acc[0][0][0] + acc[0][0][2] + acc[0][1][0] + acc[0][1][2];
        const float ghr1 = acc[0][0][1] + acc[0][0][3] + acc[0][1][1] + acc[0][1][3];
        const float ghz0 = acc[1][0][0] + acc[1][0][2] + acc[1][1][0] + acc[1][1][2];
        const float ghz1 = acc[1][0][1] + acc[1][0][3] + acc[1][1][1] + acc[1][1][3];
        const float ghn0 = acc[2][0][0] + acc[2][0][2] + acc[2][1][0] + acc[2][1][2];
        const float ghn1 = acc[2][0][1] + acc[2][0][3] + acc[2][1][1] + acc[2][1][3];
        const float r0 = fsig(gr0 + ghr0 + bias_r);
        const float z0 = fsig(gz0 + ghz0 + bias_z);
        const float nv0 = ftanh(gn0v + bihn + r0 * (ghn0 + bhhn));
        const float hn0 = (1.0f - z0) * nv0 + z0 * h0;
        const float r1 = fsig(gr1 + ghr1 + bias_r);
        const float z1 = fsig(gz1 + ghz1 + bias_z);
        const float nv1 = ftanh(gn1v + bihn + r1 * (ghn1 + bhhn));
        const float hn1 = (1.0f - z1) * nv1 + z1 * h1;
        h0 = hn0; h1 = hn1;
        const int nb = (tt + 1) & 1;
        const unsigned short hh0 = bf16hi(hn0), hh1 = bf16hi(hn1);
        const unsigned short hl0 = bf16hi(hn0 - bf2f(hh0));
        const unsigned short hl1 = bf16hi(hn1 - bf2f(hh1));
        hs[nb][c] = hh0;         hs[nb][128 + c] = hh1;
        hs[nb][256 + c] = hl0;   hs[nb][384 + c] = hl1;
        const int hb = (tt * 2) * 128 + c;
        hbh[g & 1][hb] = hh0;       hbh[g & 1][hb + 128] = hh1;
        hbl[g & 1][hb] = hl0;       hbl[g & 1][hb + 128] = hl1;
      }

      // step 7: commit staged X for next group, then issue loads for g+2
      if (tt == 7 && g + 1 < 64) {
        store_xr((g + 1) & 1);       // data-dep vmcnt wait on xr only
        if (g + 2 < 64) load_xr((g + 2) * 8);
      }
      step_barrier();
    }
  }
  // final flush (group 63, 8-step buffer: timesteps 504..511)
  flush_h(1, 504);
}

// -------------------------------------------------------------------------
// keys = H @ aWk^T + abk, split-bf16 MFMA. Output Kbt in (B, T, H) order
// (bf16 RNE) so each decoder block reads a CONTIGUOUS 128 KB slice.
// -------------------------------------------------------------------------
__global__ __launch_bounds__(256) void keys_gemm(
    const unsigned short* __restrict__ Ahi, const unsigned short* __restrict__ Alo,
    const float* __restrict__ aWk, const float* __restrict__ abk,
    unsigned short* __restrict__ Kbt)
{
  __shared__ unsigned short Ah[64 * 40], Al[64 * 40];
  __shared__ unsigned short Bh[128 * 136], Bl[128 * 136];
  const int tid  = threadIdx.x;
  const int wave = tid >> 6, lane = tid & 63;
  const int quad = lane >> 4, l16 = lane & 15;
  const size_t m0 = (size_t)blockIdx.x * 64;

  for (int i = tid; i < 16384; i += 256) {
    const float v = aWk[i];
    const unsigned short h = bf16hi(v);
    const int r = i >> 7, k = i & 127;
    Bh[r * 136 + k] = h;
    Bl[r * 136 + k] = bf16hi(v - bf2f(h));
  }

  f32x4 acc[8];
  #pragma unroll
  for (int i = 0; i < 8; ++i) acc[i] = (f32x4){0.f, 0.f, 0.f, 0.f};
  float bias[8];
  #pragma unroll
  for (int nt = 0; nt < 8; ++nt) bias[nt] = abk[nt * 16 + l16];

  const int r = tid >> 2, c8 = (tid & 3) * 8;
  for (int kc = 0; kc < 128; kc += 32) {
    __syncthreads();
    const size_t src = (m0 + r) * 128 + kc + c8;
    *(uint4*)&Ah[r * 40 + c8] = *(const uint4*)&Ahi[src];
    *(uint4*)&Al[r * 40 + c8] = *(const uint4*)&Alo[src];
    __syncthreads();
    const short8 a_hi = *(const short8*)&Ah[(wave * 16 + l16) * 40 + quad * 8];
    const short8 a_lo = *(const short8*)&Al[(wave * 16 + l16) * 40 + quad * 8];
    #pragma unroll
    for (int nt = 0; nt < 8; ++nt) {
      const short8 b_hi = *(const short8*)&Bh[(nt * 16 + l16) * 136 + kc + quad * 8];
      const short8 b_lo = *(const short8*)&Bl[(nt * 16 + l16) * 136 + kc + quad * 8];
      acc[nt] = __builtin_amdgcn_mfma_f32_16x16x32_bf16(a_hi, b_hi, acc[nt], 0, 0, 0);
      acc[nt] = __builtin_amdgcn_mfma_f32_16x16x32_bf16(a_hi, b_lo, acc[nt], 0, 0, 0);
      acc[nt] = __builtin_amdgcn_mfma_f32_16x16x32_bf16(a_lo, b_hi, acc[nt], 0, 0, 0);
    }
  }
  #pragma unroll
  for (int nt = 0; nt < 8; ++nt) {
    #pragma unroll
    for (int reg = 0; reg < 4; ++reg) {
      const size_t m = m0 + wave * 16 + quad * 4 + reg;   // m = t*B + b
      const size_t b = m & 511, t = m >> 9;
      const int n = nt * 16 + l16;
      Kbt[(b * T_LEN + t) * 128 + n] = bf16hi(acc[nt][reg] + bias[nt]);
    }
  }
}

// -------------------------------------------------------------------------
// Stash last hidden state h_T (fp32) before Hlo is recycled as H_bt.
// -------------------------------------------------------------------------
__global__ __launch_bounds__(512) void save_lasth(
    const unsigned short* __restrict__ Hhi, const unsigned short* __restrict__ Hlo,
    float* __restrict__ lastH)
{
  const int i = blockIdx.x * 512 + threadIdx.x;   // 65536 = 512 b x 128 c
  const size_t src = ((size_t)(T_LEN - 1) * B_SZ) * 128 + i;
  lastH[i] = bf2f(Hhi[src]) + bf2f(Hlo[src]);
}

// -------------------------------------------------------------------------
// Transpose Hhi (T,B,H) -> H_bt (B,T,H) so decoder ctx reads contiguous.
// Grid 4096: blk>>3 = b, blk&7 = 64-timestep group. 256 thr, 4 uint4 each.
// -------------------------------------------------------------------------
__global__ __launch_bounds__(256) void transpose_h(
    const unsigned short* __restrict__ Hhi, unsigned short* __restrict__ Hbt)
{
  const int b  = blockIdx.x >> 3;
  const int tg = blockIdx.x & 7;
  #pragma unroll
  for (int j = 0; j < 4; ++j) {
    const int id = threadIdx.x * 4 + j;
    const int tl = id >> 4;            // 0..63
    const int ch = (id & 15) * 8;      // 16-B chunk
    const int t  = tg * 64 + tl;
    const uint4 v = *(const uint4*)&Hhi[((size_t)t * B_SZ + b) * 128 + ch];
    *(uint4*)&Hbt[((size_t)b * T_LEN + t) * 128 + ch] = v;
  }
}

// -------------------------------------------------------------------------
// Decoder v5: one block per batch row; K and H in (B,T,H) order -> each
// block's 2x128KB working set is L2/L3-resident across the 8 steps.
// -------------------------------------------------------------------------
__global__ __launch_bounds__(512) void decoder(
    const unsigned short* __restrict__ Hbt,
    const unsigned short* __restrict__ Kbt,
    const float* __restrict__ lastH,
    const float* __restrict__ aWq, const float* __restrict__ abq,
    const float* __restrict__ av,
    const float* __restrict__ dwih, const float* __restrict__ dwhh,
    const float* __restrict__ dbih, const float* __restrict__ dbhh,
    const float* __restrict__ lng, const float* __restrict__ lnb,
    const float* __restrict__ w1, const float* __restrict__ b1,
    const float* __restrict__ w2, const float* __restrict__ b2,
    float* __restrict__ out)
{
  __shared__ float h_s[128], q_s[128], av_s[128], s_s[512], w_s[512];
  __shared__ float part[8][128], u_s[256], gx_s[384], gh_s[384], y_s[128];
  __shared__ float red[16];
  const int b = blockIdx.x, tid = threadIdx.x;
  const int wave = tid >> 6, lane = tid & 63;
  const int tslot = lane >> 4, ks = lane & 15;

  if (tid < 128) {
    h_s[tid] = lastH[(size_t)b * 128 + tid];
    av_s[tid] = av[tid];
  }
  __syncthreads();

  for (int step = 0; step < NSTEP; ++step) {
    if (tid < 128) {
      float acc = abq[tid];
      const float* wr = &aWq[(size_t)tid * 128];
      #pragma unroll 8
      for (int k4 = 0; k4 < 32; ++k4) {
        const float4 hv = *(const float4*)&h_s[k4 * 4];
        const float4 wv = *(const float4*)&wr[k4 * 4];
        acc += hv.x * wv.x + hv.y * wv.y + hv.z * wv.z + hv.w * wv.w;
      }
      q_s[tid] = acc;
    }
    __syncthreads();
    #pragma unroll 2
    for (int it = 0; it < 16; ++it) {
      const int t = it * 32 + wave * 4 + tslot;
      const size_t kb = ((size_t)b * T_LEN + t) * 128 + ks * 8;
      const uint4 uh = *(const uint4*)&Kbt[kb];
      const float4 q0 = *(const float4*)&q_s[ks * 8];
      const float4 q1 = *(const float4*)&q_s[ks * 8 + 4];
      const float4 a0 = *(const float4*)&av_s[ks * 8];
      const float4 a1 = *(const float4*)&av_s[ks * 8 + 4];
      float acc = ftanh(bflo(uh.x) + q0.x) * a0.x + ftanh(bfhi(uh.x) + q0.y) * a0.y
                + ftanh(bflo(uh.y) + q0.z) * a0.z + ftanh(bfhi(uh.y) + q0.w) * a0.w
                + ftanh(bflo(uh.z) + q1.x) * a1.x + ftanh(bfhi(uh.z) + q1.y) * a1.y
                + ftanh(bflo(uh.w) + q1.z) * a1.z + ftanh(bfhi(uh.w) + q1.w) * a1.w;
      acc = row_sum16(acc);
      if (ks == 0) s_s[t] = acc;
    }
    __syncthreads();
    {
      const float sv = s_s[tid];
      float mx = sv;
      #pragma unroll
      for (int o = 32; o; o >>= 1) mx = fmaxf(mx, __shfl_xor(mx, o, 64));
      if (lane == 0) red[wave] = mx;
      __syncthreads();
      mx = red[0];
      #pragma unroll
      for (int i = 1; i < 8; ++i) mx = fmaxf(mx, red[i]);
      const float e = __expf(sv - mx);
      float sm = e;
      #pragma unroll
      for (int o = 32; o; o >>= 1) sm += __shfl_xor(sm, o, 64);
      if (lane == 0) red[8 + wave] = sm;
      __syncthreads();
      float tot = red[8];
      #pragma unroll
      for (int i = 1; i < 8; ++i) tot += red[8 + i];
      w_s[tid] = e / tot;
    }
    __syncthreads();
    {
      const int th = tid >> 6;
      const int c2 = (tid & 63) * 2;
      float acc0 = 0.0f, acc1 = 0.0f;
      #pragma unroll 4
      for (int q = 0; q < 64; ++q) {
        const int t = th * 64 + q;
        const unsigned u = *(const unsigned*)&Hbt[((size_t)b * T_LEN + t) * 128 + c2];
        const float wt = w_s[t];
        acc0 += wt * bflo(u);
        acc1 += wt * bfhi(u);
      }
      part[th][c2] = acc0;
      part[th][c2 + 1] = acc1;
    }
    __syncthreads();
    if (tid < 128) {
      float s = part[0][tid];
      #pragma unroll
      for (int i = 1; i < 8; ++i) s += part[i][tid];
      u_s[tid] = s;
      u_s[128 + tid] = h_s[tid];
    }
    __syncthreads();
    if (tid < 384) {
      const int j = tid;
      float gxv = dbih[j], ghv = dbhh[j];
      const float* wxr = &dwih[(size_t)j * 256];
      const float* whr = &dwhh[(size_t)j * 128];
      #pragma unroll 8
      for (int k4 = 0; k4 < 64; ++k4) {
        const float4 uv = *(const float4*)&u_s[k4 * 4];
        const float4 wv = *(const float4*)&wxr[k4 * 4];
        gxv += uv.x * wv.x + uv.y * wv.y + uv.z * wv.z + uv.w * wv.w;
      }
      #pragma unroll 8
      for (int k4 = 0; k4 < 32; ++k4) {
        const float4 hv = *(const float4*)&h_s[k4 * 4];
        const float4 wv = *(const float4*)&whr[k4 * 4];
        ghv += hv.x * wv.x + hv.y * wv.y + hv.z * wv.z + hv.w * wv.w;
      }
      gx_s[j] = gxv; gh_s[j] = ghv;
    }
    __syncthreads();
    if (tid < 128) {
      const float r = fsig(gx_s[tid] + gh_s[tid]);
      const float z = fsig(gx_s[128 + tid] + gh_s[128 + tid]);
      const float n = ftanh(gx_s[256 + tid] + r * gh_s[256 + tid]);
      const float hn = (1.0f - z) * n + z * h_s[tid];
      h_s[tid] = hn;
      float s1 = hn, s2 = hn * hn;
      #pragma unroll
      for (int o = 32; o; o >>= 1) { s1 += __shfl_xor(s1, o, 64); s2 += __shfl_xor(s2, o, 64); }
      if ((tid & 63) == 0) { red[tid >> 6] = s1; red[4 + (tid >> 6)] = s2; }
    }
    __syncthreads();
    if (tid < 128) {
      const float hn  = h_s[tid];
      const float mu  = (red[0] + red[1]) * (1.0f / 128.0f);
      const float var = (red[4] + red[5]) * (1.0f / 128.0f) - mu * mu;
      y_s[tid] = (hn - mu) / sqrtf(var + 1e-5f) * lng[tid] + lnb[tid];
    }
    __syncthreads();
    if (tid < 64) {
      float acc = b1[tid];
      const float* wr = &w1[(size_t)tid * 128];
      #pragma unroll 8
      for (int k4 = 0; k4 < 32; ++k4) {
        const float4 yv = *(const float4*)&y_s[k4 * 4];
        const float4 wv = *(const float4*)&wr[k4 * 4];
        acc += yv.x * wv.x + yv.y * wv.y + yv.z * wv.z + yv.w * wv.w;
      }
      acc = fmaxf(acc, 0.0f);
      float v = acc * w2[tid];
      #pragma unroll
      for (int o = 32; o; o >>= 1) v += __shfl_xor(v, o, 64);
      if (tid == 0) out[(size_t)b * NSTEP + step] = v + b2[0];
    }
    __syncthreads();
  }
}

// -------------------------------------------------------------------------
extern "C" void kernel_launch(void* const* d_in, const int* in_sizes, int n_in,
                              void* d_out, int out_size, void* d_ws, size_t ws_size,
                              hipStream_t stream)
{
  (void)in_sizes; (void)n_in; (void)out_size; (void)ws_size;
  const float* x    = (const float*)d_in[0];
  const float* ewih[3] = {(const float*)d_in[1], (const float*)d_in[5], (const float*)d_in[9]};
  const float* ewhh[3] = {(const float*)d_in[2], (const float*)d_in[6], (const float*)d_in[10]};
  const float* ebih[3] = {(const float*)d_in[3], (const float*)d_in[7], (const float*)d_in[11]};
  const float* ebhh[3] = {(const float*)d_in[4], (const float*)d_in[8], (const float*)d_in[12]};
  const float* aWq  = (const float*)d_in[13];
  const float* abq  = (const float*)d_in[14];
  const float* aWk  = (const float*)d_in[15];
  const float* abk  = (const float*)d_in[16];
  const float* av   = (const float*)d_in[17];
  const float* dwih = (const float*)d_in[18];
  const float* dwhh = (const float*)d_in[19];
  const float* dbih = (const float*)d_in[20];
  const float* dbhh = (const float*)d_in[21];
  const float* lng  = (const float*)d_in[22];
  const float* lnb  = (const float*)d_in[23];
  const float* w1   = (const float*)d_in[24];
  const float* b1   = (const float*)d_in[25];
  const float* w2   = (const float*)d_in[26];
  const float* b2   = (const float*)d_in[27];

  const size_t HN = (size_t)T_LEN * B_SZ * H_DIM;               // 33,554,432 elems
  unsigned short* Hhi = (unsigned short*)d_ws;                  // 64 MiB (T,B,H)
  unsigned short* Hlo = Hhi + HN;                               // 64 MiB (later: H_bt)
  float* regionC = (float*)(Hlo + HN);                          // 128 MiB
  unsigned short* Whi = (unsigned short*)(regionC + 25165824 + 65536);
  unsigned short* Wlo = Whi + 122880;
  unsigned short* Kbt = (unsigned short*)regionC;               // decode: 64 MiB
  float* lastH = regionC + 16777216;                            // +64 MiB, 256 KiB

  prep_split<<<dim3(480), dim3(256), 0, stream>>>(ewih[0], ewih[1], ewih[2], Whi, Wlo);

  rec_fused<1><<<dim3(256), dim3(512), 0, stream>>>(
      x, nullptr, nullptr, Whi, Wlo,
      ewhh[0], ebih[0], ebhh[0], Hhi, Hlo);
  rec_fused<0><<<dim3(256), dim3(512), 0, stream>>>(
      nullptr, Hhi, Hlo, Whi + 24576, Wlo + 24576,
      ewhh[1], ebih[1], ebhh[1], Hhi, Hlo);
  rec_fused<0><<<dim3(256), dim3(512), 0, stream>>>(
      nullptr, Hhi, Hlo, Whi + 73728, Wlo + 73728,
      ewhh[2], ebih[2], ebhh[2], Hhi, Hlo);

  keys_gemm<<<dim3(4096), dim3(256), 0, stream>>>(Hhi, Hlo, aWk, abk, Kbt);
  save_lasth<<<dim3(128), dim3(512), 0, stream>>>(Hhi, Hlo, lastH);
  // Hlo is dead after keys_gemm + save_lasth: recycle it as H_bt (B,T,H)
  transpose_h<<<dim3(4096), dim3(256), 0, stream>>>(Hhi, Hlo);
  decoder<<<dim3(512), dim3(512), 0, stream>>>(
      Hlo, Kbt, lastH, aWq, abq, av, dwih, dwhh, dbih, dbhh,
      lng, lnb, w1, b1, w2, b2, (float*)d_out);
}

// Round 8
// 2332.306 us; speedup vs baseline: 1.3406x; 1.0245x over previous
//
#include <hip/hip_runtime.h>
#include <hip/hip_bf16.h>
#include <cstdint>
#include <cstddef>

#define T_LEN 512
#define B_SZ  512
#define F_IN  64
#define H_DIM 128
#define NSTEP 8

typedef __attribute__((ext_vector_type(8))) short short8;
typedef __attribute__((ext_vector_type(4))) float f32x4;

__device__ __forceinline__ float fsig(float x) { return 1.0f / (1.0f + __expf(-x)); }
__device__ __forceinline__ float ftanh(float x) {
  float e = __expf(-2.0f * fabsf(x));
  float t = (1.0f - e) / (1.0f + e);
  return copysignf(t, x);
}
__device__ __forceinline__ unsigned short bf16hi(float x) {
  __hip_bfloat16 h = __float2bfloat16(x);
  return *(unsigned short*)&h;
}
__device__ __forceinline__ float bf2f(unsigned short u) {
  return __uint_as_float(((unsigned)u) << 16);
}
__device__ __forceinline__ float bflo(unsigned u) { return __uint_as_float(u << 16); }
__device__ __forceinline__ float bfhi(unsigned u) { return __uint_as_float(u & 0xffff0000u); }

// lgkm-only barrier: LDS consistency without draining vmcnt (flush stores and
// prefetch loads stay in flight across steps).
__device__ __forceinline__ void step_barrier() {
  asm volatile("s_waitcnt lgkmcnt(0)" ::: "memory");
  __builtin_amdgcn_s_barrier();
  asm volatile("" ::: "memory");
}

// DPP cross-lane add within 16-lane rows (decoder scores)
template <int CTRL>
__device__ __forceinline__ float dpp_add(float v) {
  int p = __builtin_amdgcn_update_dpp(0, __float_as_int(v), CTRL, 0xF, 0xF, true);
  return v + __int_as_float(p);
}
__device__ __forceinline__ float row_sum16(float v) {
  v = dpp_add<0xB1>(v);
  v = dpp_add<0x4E>(v);
  v = dpp_add<0x124>(v);
  v = dpp_add<0x128>(v);
  return v;
}

// split 8 consecutive fp32 into bf16 hi/lo short8 fragments
__device__ __forceinline__ void split8(const float* p, short8& hi, short8& lo) {
  #pragma unroll
  for (int i = 0; i < 8; ++i) {
    const float v = p[i];
    const unsigned short h = bf16hi(v);
    hi[i] = (short)h;
    lo[i] = (short)bf16hi(v - bf2f(h));
  }
}

// split two adjacent float4 (8 fp32) into bf16 hi/lo short8 fragments
__device__ __forceinline__ void split_f4pair(const float4 a, const float4 b,
                                             short8& hi, short8& lo) {
  const float v[8] = {a.x, a.y, a.z, a.w, b.x, b.y, b.z, b.w};
  #pragma unroll
  for (int j = 0; j < 8; ++j) {
    const unsigned short h = bf16hi(v[j]);
    hi[j] = (short)h;
    lo[j] = (short)bf16hi(v[j] - bf2f(h));
  }
}

// -------------------------------------------------------------------------
// Split the 3 encoder w_ih matrices into bf16 hi/lo pairs (one-time prep).
// -------------------------------------------------------------------------
__global__ __launch_bounds__(256) void prep_split(
    const float* __restrict__ w0, const float* __restrict__ w1,
    const float* __restrict__ w2,
    unsigned short* __restrict__ hi, unsigned short* __restrict__ lo)
{
  const int i = blockIdx.x * 256 + threadIdx.x;
  if (i >= 122880) return;
  float v = (i < 24576) ? w0[i] : ((i < 73728) ? w1[i - 24576] : w2[i - 73728]);
  const unsigned short h = bf16hi(v);
  hi[i] = h;
  lo[i] = bf16hi(v - bf2f(h));
}

// -------------------------------------------------------------------------
// Fused GRU layer v7 = v6 + three LDS/VALU cuts (MFMA count unchanged):
//  1. hs XOR-swizzle: phys granule = row*32 + ((quad+row)&3)*8 shorts ->
//     per-ck A-read goes 4-way -> 2-way (free). Since A rows 4-15 duplicate
//     rows 0-3, EVERY quad's C regs 0-3 hold identical gate inputs: all
//     lanes compute gates (no divergence) and each quad writes its own hs
//     slot {hh0,hh1,hl0,hl1} with ONE all-lane ds_write_b16.
//  2. gxlds repack [tt][r][c][4] (r-stride 520, tt-stride 1040 floats) with
//     r/z/n biases folded in at the boundary: 6 ds_read_b32 -> 2 b128/step.
//  3. X staged directly in registers (16 VGPR), Xraw LDS deleted.
// hbuf writes + flush stay byte-identical to v6 (proven). LDS 150.0 KB.
// -------------------------------------------------------------------------
template <int IS_L0>
__global__ __launch_bounds__(512, 2) void rec_fused(
    const float* x,                         // layer0 input (B,T,F), else unused
    const unsigned short* Xhi,              // layers>=1: prev-layer H hi (T,B,H)
    const unsigned short* Xlo,
    const unsigned short* __restrict__ Wih_hi,  // (384, KD) bf16 hi
    const unsigned short* __restrict__ Wih_lo,  // (384, KD) bf16 lo
    const float* __restrict__ w_hh, const float* __restrict__ b_ih,
    const float* __restrict__ b_hh,
    unsigned short* Hhi, unsigned short* Hlo)   // out (T,B,H)
{
  constexpr int KD   = IS_L0 ? 64 : 128;
  constexpr int NCK  = KD / 32;
  constexpr int WROW = KD * 2;              // bytes per W row in LDS
  constexpr int WGRAN = WROW / 16;          // 16B granules per W row

  __shared__ unsigned short Wlds[384 * KD];          // w_ih hi, swizzled
  __shared__ float gxldsF[8 * 1040];                 // [tt][r(520)][c*4+g], bias-folded
  __shared__ unsigned short hbh[2][2048], hbl[2][2048]; // h history (8t x 2r x 128)
  __shared__ unsigned short hs[2][512];              // packed h, XOR-swizzled

  const int tid  = threadIdx.x;
  const int wv   = tid >> 6, lane = tid & 63;
  const int quad = lane >> 4, l16 = lane & 15;
  const int b0   = blockIdx.x * 2;
  const int c    = wv * 16 + l16;          // owned channel

  const f32x4 z4 = (f32x4){0.f, 0.f, 0.f, 0.f};

  // ---- stage w_ih hi into LDS (swizzled: granule ^= row & (WGRAN-1)) ----
  {
    unsigned char* wb = (unsigned char*)Wlds;
    #pragma unroll
    for (int k = 0; k < (384 * WGRAN) / 512; ++k) {
      const int idx = k * 512 + tid;
      const int row = idx / WGRAN;
      const int gg  = idx % WGRAN;
      const uint4 v = *(const uint4*)&Wih_hi[(size_t)row * KD + gg * 8];
      *(uint4*)&wb[row * WROW + ((gg ^ (row & (WGRAN - 1))) * 16)] = v;
    }
  }

  // ---- w_ih lo persistent fragments ----
  short8 Wl_[3][NCK];
  #pragma unroll
  for (int g_ = 0; g_ < 3; ++g_)
    #pragma unroll
    for (int ck = 0; ck < NCK; ++ck)
      Wl_[g_][ck] = *(const short8*)&Wih_lo[(size_t)(g_ * 128 + c) * KD + ck * 32 + quad * 8];

  // ---- w_hh persistent fragments (split from fp32) ----
  short8 Bh[3][4], Bl[3][4];
  #pragma unroll
  for (int g_ = 0; g_ < 3; ++g_)
    #pragma unroll
    for (int ck = 0; ck < 4; ++ck)
      split8(&w_hh[(size_t)(g_ * 128 + c) * 128 + ck * 32 + quad * 8],
             Bh[g_][ck], Bl[g_][ck]);

  // biases: ALL lanes (gate compute is all-lane now)
  const float bias_r = b_ih[c] + b_hh[c];
  const float bias_z = b_ih[c + 128] + b_hh[c + 128];
  const float bihn   = b_ih[c + 256];
  const float bhhn   = b_hh[c + 256];
  float h0 = 0.f, h1 = 0.f;
  hs[0][tid & 511] = 0;                    // zero initial packed-h buffer

  // per-lane hs addresses (hoisted; swizzle verified 2-way):
  //   generic phys(r, gk, j) = (gk>>2)*128 + r*32 + (((gk&3)+r)&3)*8 + j
  const int arow = l16 & 3;
  const int K0   = arow * 32 + (((quad + arow) & 3) * 8);   // A-read base
  const int hswr = ((c >> 5) * 128) + quad * 32
                 + (((((c >> 3) & 3) + quad) & 3) * 8) + (c & 7); // slot write

  // ---- X in registers (16 VGPR), one group in flight ----
  uint4  xh[4], xl[4];      // KD=128
  float4 xf[4];             // KD=64
  auto load_x = [&](int tgn) {
    if constexpr (IS_L0) {
      #pragma unroll
      for (int ck = 0; ck < 2; ++ck) {
        const size_t base =
            ((size_t)(b0 + (l16 & 1)) * T_LEN + tgn + (l16 >> 1)) * 64 + ck * 32 + quad * 8;
        xf[ck * 2]     = *(const float4*)&x[base];
        xf[ck * 2 + 1] = *(const float4*)&x[base + 4];
      }
    } else {
      #pragma unroll
      for (int ck = 0; ck < 4; ++ck) {
        const size_t base =
            ((size_t)(tgn + (l16 >> 1)) * B_SZ + b0 + (l16 & 1)) * 128 + ck * 32 + quad * 8;
        xh[ck] = *(const uint4*)&Xhi[base];
        xl[ck] = *(const uint4*)&Xlo[base];
      }
    }
  };

  const int t8 = tid & 255;
  auto flush_h = [&](int buf, int tp) {
    const int ft = t8 >> 5, fr = (t8 >> 4) & 1, fs = t8 & 15;
    const size_t go = ((size_t)(tp + ft) * B_SZ + b0 + fr) * 128 + fs * 8;
    const int lo_ = (ft * 2 + fr) * 128 + fs * 8;
    if (tid < 256) *(uint4*)&Hhi[go] = *(const uint4*)&hbh[buf][lo_];
    else           *(uint4*)&Hlo[go] = *(const uint4*)&hbl[buf][lo_];
  };

  load_x(0);
  __syncthreads();   // Wlds + hs zeros visible

  for (int g = 0; g < 64; ++g) {
    // ---- flush previous group's h history (coalesced) ----
    if (g > 0) flush_h((g - 1) & 1, g * 8 - 8);

    // ---- gx for this group: A = 8 timesteps x 2 batch rows (from regs) ----
    short8 Xhf[2], Xlf[2];
    if constexpr (IS_L0) {
      split_f4pair(xf[0], xf[1], Xhf[0], Xlf[0]);
      split_f4pair(xf[2], xf[3], Xhf[1], Xlf[1]);
    }
    {
      f32x4 ax[3][2];
      const unsigned char* wb = (const unsigned char*)Wlds;
      #pragma unroll
      for (int g_ = 0; g_ < 3; ++g_) { ax[g_][0] = z4; ax[g_][1] = z4; }
      #pragma unroll
      for (int ck = 0; ck < NCK; ++ck) {
        const int p = (NCK == 4) ? (ck >> 1) : ck;
        #pragma unroll
        for (int g_ = 0; g_ < 3; ++g_) {
          const int n = g_ * 128 + c;
          const short8 wh = *(const short8*)&wb[n * WROW + (((ck * 4 + quad) ^ (n & (WGRAN - 1))) * 16)];
          short8 ah, al;
          if constexpr (IS_L0) { ah = Xhf[ck]; al = Xlf[ck]; }
          else { ah = *(const short8*)&xh[ck]; al = *(const short8*)&xl[ck]; }
          ax[g_][p] = __builtin_amdgcn_mfma_f32_16x16x32_bf16(ah, wh, ax[g_][p], 0, 0, 0);
          ax[g_][p] = __builtin_amdgcn_mfma_f32_16x16x32_bf16(ah, Wl_[g_][ck], ax[g_][p], 0, 0, 0);
          ax[g_][p] = __builtin_amdgcn_mfma_f32_16x16x32_bf16(al, wh, ax[g_][p], 0, 0, 0);
        }
      }
      // reload X regs for the NEXT group (WAR: after all gx MFMAs)
      if (g + 1 < 64) load_x((g + 1) * 8);
      // park gx+bias in LDS: D row rr=quad*4+reg -> (tt=quad*2+(reg>>1), r=reg&1)
      #pragma unroll
      for (int g_ = 0; g_ < 3; ++g_) {
        const float bg = (g_ == 0) ? bias_r : (g_ == 1) ? bias_z : bihn;
        #pragma unroll
        for (int reg = 0; reg < 4; ++reg) {
          const int tt_ = quad * 2 + (reg >> 1);
          const int r_  = reg & 1;
          gxldsF[tt_ * 1040 + r_ * 520 + c * 4 + g_] =
              ax[g_][0][reg] + ax[g_][1][reg] + bg;
        }
      }
    }
    step_barrier();   // gxlds visible; hbuf flushed reads done

    // ---- 8 recurrence steps: pure LDS + MFMA + VALU ----
    #pragma unroll
    for (int tt = 0; tt < 8; ++tt) {
      // gate inputs (bias-folded), ALL lanes, 2x ds_read_b128
      const float4 ga = *(const float4*)&gxldsF[tt * 1040 + c * 4];
      const float4 gb = *(const float4*)&gxldsF[tt * 1040 + 520 + c * 4];

      // packed-h A-fragments, swizzled (2-way banks); rows 4-15 duplicate
      short8 Af[4];
      #pragma unroll
      for (int ck = 0; ck < 4; ++ck)
        Af[ck] = *(const short8*)&hs[tt & 1][ck * 128 + K0];

      // gh MFMAs: 3 gates x 2 partials x {2ck x (B_hi,B_lo)}
      f32x4 acc[3][2];
      #pragma unroll
      for (int g_ = 0; g_ < 3; ++g_) {
        #pragma unroll
        for (int p = 0; p < 2; ++p) {
          const int k0 = p * 2;
          acc[g_][p] = __builtin_amdgcn_mfma_f32_16x16x32_bf16(Af[k0], Bh[g_][k0], z4, 0, 0, 0);
          acc[g_][p] = __builtin_amdgcn_mfma_f32_16x16x32_bf16(Af[k0], Bl[g_][k0], acc[g_][p], 0, 0, 0);
          acc[g_][p] = __builtin_amdgcn_mfma_f32_16x16x32_bf16(Af[k0 + 1], Bh[g_][k0 + 1], acc[g_][p], 0, 0, 0);
          acc[g_][p] = __builtin_amdgcn_mfma_f32_16x16x32_bf16(Af[k0 + 1], Bl[g_][k0 + 1], acc[g_][p], 0, 0, 0);
        }
      }

      // gates: ALL lanes (every quad's C regs 0-3 are identical)
      const float ghr0 = acc[0][0][0] + acc[0][0][2] + acc[0][1][0] + acc[0][1][2];
      const float ghr1 = acc[0][0][1] + acc[0][0][3] + acc[0][1][1] + acc[0][1][3];
      const float ghz0 = acc[1][0][0] + acc[1][0][2] + acc[1][1][0] + acc[1][1][2];
      const float ghz1 = acc[1][0][1] + acc[1][0][3] + acc[1][1][1] + acc[1][1][3];
      const float ghn0 = acc[2][0][0] + acc[2][0][2] + acc[2][1][0] + acc[2][1][2];
      const float ghn1 = acc[2][0][1] + acc[2][0][3] + acc[2][1][1] + acc[2][1][3];
      const float r0 = fsig(ga.x + ghr0);
      const float z0 = fsig(ga.y + ghz0);
      const float nv0 = ftanh(ga.z + r0 * (ghn0 + bhhn));
      const float hn0 = (1.0f - z0) * nv0 + z0 * h0;
      const float r1 = fsig(gb.x + ghr1);
      const float z1 = fsig(gb.y + ghz1);
      const float nv1 = ftanh(gb.z + r1 * (ghn1 + bhhn));
      const float hn1 = (1.0f - z1) * nv1 + z1 * h1;
      h0 = hn0; h1 = hn1;

      // hs slot write: quad q writes its slot {hh0,hh1,hl0,hl1}[q]
      const int nb = (tt + 1) & 1;
      const float hnsel = (quad & 1) ? hn1 : hn0;
      const unsigned short uh = bf16hi(hnsel);
      unsigned short val = uh;
      if (quad >= 2) val = bf16hi(hnsel - bf2f(uh));
      hs[nb][hswr] = val;

      // hbuf history (unchanged from v6: quad0-masked, proven flush)
      if (quad == 0) {
        const unsigned short hh0 = uh;   // quad0: hnsel == hn0
        const unsigned short hl0 = bf16hi(hn0 - bf2f(hh0));
        const unsigned short hh1 = bf16hi(hn1);
        const unsigned short hl1 = bf16hi(hn1 - bf2f(hh1));
        const int hb = (tt * 2) * 128 + c;
        hbh[g & 1][hb] = hh0;       hbh[g & 1][hb + 128] = hh1;
        hbl[g & 1][hb] = hl0;       hbl[g & 1][hb + 128] = hl1;
      }
      step_barrier();
    }
  }
  // final flush (group 63, 8-step buffer: timesteps 504..511)
  flush_h(1, 504);
}

// -------------------------------------------------------------------------
// keys = H @ aWk^T + abk, split-bf16 MFMA. Output Kbt in (B, T, H) order
// (bf16 RNE) so each decoder block reads a CONTIGUOUS 128 KB slice.
// -------------------------------------------------------------------------
__global__ __launch_bounds__(256) void keys_gemm(
    const unsigned short* __restrict__ Ahi, const unsigned short* __restrict__ Alo,
    const float* __restrict__ aWk, const float* __restrict__ abk,
    unsigned short* __restrict__ Kbt)
{
  __shared__ unsigned short Ah[64 * 40], Al[64 * 40];
  __shared__ unsigned short Bh[128 * 136], Bl[128 * 136];
  const int tid  = threadIdx.x;
  const int wave = tid >> 6, lane = tid & 63;
  const int quad = lane >> 4, l16 = lane & 15;
  const size_t m0 = (size_t)blockIdx.x * 64;

  for (int i = tid; i < 16384; i += 256) {
    const float v = aWk[i];
    const unsigned short h = bf16hi(v);
    const int r = i >> 7, k = i & 127;
    Bh[r * 136 + k] = h;
    Bl[r * 136 + k] = bf16hi(v - bf2f(h));
  }

  f32x4 acc[8];
  #pragma unroll
  for (int i = 0; i < 8; ++i) acc[i] = (f32x4){0.f, 0.f, 0.f, 0.f};
  float bias[8];
  #pragma unroll
  for (int nt = 0; nt < 8; ++nt) bias[nt] = abk[nt * 16 + l16];

  const int r = tid >> 2, c8 = (tid & 3) * 8;
  for (int kc = 0; kc < 128; kc += 32) {
    __syncthreads();
    const size_t src = (m0 + r) * 128 + kc + c8;
    *(uint4*)&Ah[r * 40 + c8] = *(const uint4*)&Ahi[src];
    *(uint4*)&Al[r * 40 + c8] = *(const uint4*)&Alo[src];
    __syncthreads();
    const short8 a_hi = *(const short8*)&Ah[(wave * 16 + l16) * 40 + quad * 8];
    const short8 a_lo = *(const short8*)&Al[(wave * 16 + l16) * 40 + quad * 8];
    #pragma unroll
    for (int nt = 0; nt < 8; ++nt) {
      const short8 b_hi = *(const short8*)&Bh[(nt * 16 + l16) * 136 + kc + quad * 8];
      const short8 b_lo = *(const short8*)&Bl[(nt * 16 + l16) * 136 + kc + quad * 8];
      acc[nt] = __builtin_amdgcn_mfma_f32_16x16x32_bf16(a_hi, b_hi, acc[nt], 0, 0, 0);
      acc[nt] = __builtin_amdgcn_mfma_f32_16x16x32_bf16(a_hi, b_lo, acc[nt], 0, 0, 0);
      acc[nt] = __builtin_amdgcn_mfma_f32_16x16x32_bf16(a_lo, b_hi, acc[nt], 0, 0, 0);
    }
  }
  #pragma unroll
  for (int nt = 0; nt < 8; ++nt) {
    #pragma unroll
    for (int reg = 0; reg < 4; ++reg) {
      const size_t m = m0 + wave * 16 + quad * 4 + reg;   // m = t*B + b
      const size_t b = m & 511, t = m >> 9;
      const int n = nt * 16 + l16;
      Kbt[(b * T_LEN + t) * 128 + n] = bf16hi(acc[nt][reg] + bias[nt]);
    }
  }
}

// -------------------------------------------------------------------------
// Stash last hidden state h_T (fp32) before Hlo is recycled as H_bt.
// -------------------------------------------------------------------------
__global__ __launch_bounds__(512) void save_lasth(
    const unsigned short* __restrict__ Hhi, const unsigned short* __restrict__ Hlo,
    float* __restrict__ lastH)
{
  const int i = blockIdx.x * 512 + threadIdx.x;   // 65536 = 512 b x 128 c
  const size_t src = ((size_t)(T_LEN - 1) * B_SZ) * 128 + i;
  lastH[i] = bf2f(Hhi[src]) + bf2f(Hlo[src]);
}

// -------------------------------------------------------------------------
// Transpose Hhi (T,B,H) -> H_bt (B,T,H) so decoder ctx reads contiguous.
// -------------------------------------------------------------------------
__global__ __launch_bounds__(256) void transpose_h(
    const unsigned short* __restrict__ Hhi, unsigned short* __restrict__ Hbt)
{
  const int b  = blockIdx.x >> 3;
  const int tg = blockIdx.x & 7;
  #pragma unroll
  for (int j = 0; j < 4; ++j) {
    const int id = threadIdx.x * 4 + j;
    const int tl = id >> 4;            // 0..63
    const int ch = (id & 15) * 8;      // 16-B chunk
    const int t  = tg * 64 + tl;
    const uint4 v = *(const uint4*)&Hhi[((size_t)t * B_SZ + b) * 128 + ch];
    *(uint4*)&Hbt[((size_t)b * T_LEN + t) * 128 + ch] = v;
  }
}

// -------------------------------------------------------------------------
// Decoder: one block per batch row; K and H in (B,T,H) order -> each
// block's 2x128KB working set is L2/L3-resident across the 8 steps.
// -------------------------------------------------------------------------
__global__ __launch_bounds__(512) void decoder(
    const unsigned short* __restrict__ Hbt,
    const unsigned short* __restrict__ Kbt,
    const float* __restrict__ lastH,
    const float* __restrict__ aWq, const float* __restrict__ abq,
    const float* __restrict__ av,
    const float* __restrict__ dwih, const float* __restrict__ dwhh,
    const float* __restrict__ dbih, const float* __restrict__ dbhh,
    const float* __restrict__ lng, const float* __restrict__ lnb,
    const float* __restrict__ w1, const float* __restrict__ b1,
    const float* __restrict__ w2, const float* __restrict__ b2,
    float* __restrict__ out)
{
  __shared__ float h_s[128], q_s[128], av_s[128], s_s[512], w_s[512];
  __shared__ float part[8][128], u_s[256], gx_s[384], gh_s[384], y_s[128];
  __shared__ float red[16];
  const int b = blockIdx.x, tid = threadIdx.x;
  const int wave = tid >> 6, lane = tid & 63;
  const int tslot = lane >> 4, ks = lane & 15;

  if (tid < 128) {
    h_s[tid] = lastH[(size_t)b * 128 + tid];
    av_s[tid] = av[tid];
  }
  __syncthreads();

  for (int step = 0; step < NSTEP; ++step) {
    if (tid < 128) {
      float acc = abq[tid];
      const float* wr = &aWq[(size_t)tid * 128];
      #pragma unroll 8
      for (int k4 = 0; k4 < 32; ++k4) {
        const float4 hv = *(const float4*)&h_s[k4 * 4];
        const float4 wv = *(const float4*)&wr[k4 * 4];
        acc += hv.x * wv.x + hv.y * wv.y + hv.z * wv.z + hv.w * wv.w;
      }
      q_s[tid] = acc;
    }
    __syncthreads();
    #pragma unroll 2
    for (int it = 0; it < 16; ++it) {
      const int t = it * 32 + wave * 4 + tslot;
      const size_t kb = ((size_t)b * T_LEN + t) * 128 + ks * 8;
      const uint4 uh = *(const uint4*)&Kbt[kb];
      const float4 q0 = *(const float4*)&q_s[ks * 8];
      const float4 q1 = *(const float4*)&q_s[ks * 8 + 4];
      const float4 a0 = *(const float4*)&av_s[ks * 8];
      const float4 a1 = *(const float4*)&av_s[ks * 8 + 4];
      float acc = ftanh(bflo(uh.x) + q0.x) * a0.x + ftanh(bfhi(uh.x) + q0.y) * a0.y
                + ftanh(bflo(uh.y) + q0.z) * a0.z + ftanh(bfhi(uh.y) + q0.w) * a0.w
                + ftanh(bflo(uh.z) + q1.x) * a1.x + ftanh(bfhi(uh.z) + q1.y) * a1.y
                + ftanh(bflo(uh.w) + q1.z) * a1.z + ftanh(bfhi(uh.w) + q1.w) * a1.w;
      acc = row_sum16(acc);
      if (ks == 0) s_s[t] = acc;
    }
    __syncthreads();
    {
      const float sv = s_s[tid];
      float mx = sv;
      #pragma unroll
      for (int o = 32; o; o >>= 1) mx = fmaxf(mx, __shfl_xor(mx, o, 64));
      if (lane == 0) red[wave] = mx;
      __syncthreads();
      mx = red[0];
      #pragma unroll
      for (int i = 1; i < 8; ++i) mx = fmaxf(mx, red[i]);
      const float e = __expf(sv - mx);
      float sm = e;
      #pragma unroll
      for (int o = 32; o; o >>= 1) sm += __shfl_xor(sm, o, 64);
      if (lane == 0) red[8 + wave] = sm;
      __syncthreads();
      float tot = red[8];
      #pragma unroll
      for (int i = 1; i < 8; ++i) tot += red[8 + i];
      w_s[tid] = e / tot;
    }
    __syncthreads();
    {
      const int th = tid >> 6;
      const int c2 = (tid & 63) * 2;
      float acc0 = 0.0f, acc1 = 0.0f;
      #pragma unroll 4
      for (int q = 0; q < 64; ++q) {
        const int t = th * 64 + q;
        const unsigned u = *(const unsigned*)&Hbt[((size_t)b * T_LEN + t) * 128 + c2];
        const float wt = w_s[t];
        acc0 += wt * bflo(u);
        acc1 += wt * bfhi(u);
      }
      part[th][c2] = acc0;
      part[th][c2 + 1] = acc1;
    }
    __syncthreads();
    if (tid < 128) {
      float s = part[0][tid];
      #pragma unroll
      for (int i = 1; i < 8; ++i) s += part[i][tid];
      u_s[tid] = s;
      u_s[128 + tid] = h_s[tid];
    }
    __syncthreads();
    if (tid < 384) {
      const int j = tid;
      float gxv = dbih[j], ghv = dbhh[j];
      const float* wxr = &dwih[(size_t)j * 256];
      const float* whr = &dwhh[(size_t)j * 128];
      #pragma unroll 8
      for (int k4 = 0; k4 < 64; ++k4) {
        const float4 uv = *(const float4*)&u_s[k4 * 4];
        const float4 wv = *(const float4*)&wxr[k4 * 4];
        gxv += uv.x * wv.x + uv.y * wv.y + uv.z * wv.z + uv.w * wv.w;
      }
      #pragma unroll 8
      for (int k4 = 0; k4 < 32; ++k4) {
        const float4 hv = *(const float4*)&h_s[k4 * 4];
        const float4 wv = *(const float4*)&whr[k4 * 4];
        ghv += hv.x * wv.x + hv.y * wv.y + hv.z * wv.z + hv.w * wv.w;
      }
      gx_s[j] = gxv; gh_s[j] = ghv;
    }
    __syncthreads();
    if (tid < 128) {
      const float r = fsig(gx_s[tid] + gh_s[tid]);
      const float z = fsig(gx_s[128 + tid] + gh_s[128 + tid]);
      const float n = ftanh(gx_s[256 + tid] + r * gh_s[256 + tid]);
      const float hn = (1.0f - z) * n + z * h_s[tid];
      h_s[tid] = hn;
      float s1 = hn, s2 = hn * hn;
      #pragma unroll
      for (int o = 32; o; o >>= 1) { s1 += __shfl_xor(s1, o, 64); s2 += __shfl_xor(s2, o, 64); }
      if ((tid & 63) == 0) { red[tid >> 6] = s1; red[4 + (tid >> 6)] = s2; }
    }
    __syncthreads();
    if (tid < 128) {
      const float hn  = h_s[tid];
      const float mu  = (red[0] + red[1]) * (1.0f / 128.0f);
      const float var = (red[4] + red[5]) * (1.0f / 128.0f) - mu * mu;
      y_s[tid] = (hn - mu) / sqrtf(var + 1e-5f) * lng[tid] + lnb[tid];
    }
    __syncthreads();
    if (tid < 64) {
      float acc = b1[tid];
      const float* wr = &w1[(size_t)tid * 128];
      #pragma unroll 8
      for (int k4 = 0; k4 < 32; ++k4) {
        const float4 yv = *(const float4*)&y_s[k4 * 4];
        const float4 wv = *(const float4*)&wr[k4 * 4];
        acc += yv.x * wv.x + yv.y * wv.y + yv.z * wv.z + yv.w * wv.w;
      }
      acc = fmaxf(acc, 0.0f);
      float v = acc * w2[tid];
      #pragma unroll
      for (int o = 32; o; o >>= 1) v += __shfl_xor(v, o, 64);
      if (tid == 0) out[(size_t)b * NSTEP + step] = v + b2[0];
    }
    __syncthreads();
  }
}

// -------------------------------------------------------------------------
extern "C" void kernel_launch(void* const* d_in, const int* in_sizes, int n_in,
                              void* d_out, int out_size, void* d_ws, size_t ws_size,
                              hipStream_t stream)
{
  (void)in_sizes; (void)n_in; (void)out_size; (void)ws_size;
  const float* x    = (const float*)d_in[0];
  const float* ewih[3] = {(const float*)d_in[1], (const float*)d_in[5], (const float*)d_in[9]};
  const float* ewhh[3] = {(const float*)d_in[2], (const float*)d_in[6], (const float*)d_in[10]};
  const float* ebih[3] = {(const float*)d_in[3], (const float*)d_in[7], (const float*)d_in[11]};
  const float* ebhh[3] = {(const float*)d_in[4], (const float*)d_in[8], (const float*)d_in[12]};
  const float* aWq  = (const float*)d_in[13];
  const float* abq  = (const float*)d_in[14];
  const float* aWk  = (const float*)d_in[15];
  const float* abk  = (const float*)d_in[16];
  const float* av   = (const float*)d_in[17];
  const float* dwih = (const float*)d_in[18];
  const float* dwhh = (const float*)d_in[19];
  const float* dbih = (const float*)d_in[20];
  const float* dbhh = (const float*)d_in[21];
  const float* lng  = (const float*)d_in[22];
  const float* lnb  = (const float*)d_in[23];
  const float* w1   = (const float*)d_in[24];
  const float* b1   = (const float*)d_in[25];
  const float* w2   = (const float*)d_in[26];
  const float* b2   = (const float*)d_in[27];

  const size_t HN = (size_t)T_LEN * B_SZ * H_DIM;               // 33,554,432 elems
  unsigned short* Hhi = (unsigned short*)d_ws;                  // 64 MiB (T,B,H)
  unsigned short* Hlo = Hhi + HN;                               // 64 MiB (later: H_bt)
  float* regionC = (float*)(Hlo + HN);                          // 128 MiB
  unsigned short* Whi = (unsigned short*)(regionC + 25165824 + 65536);
  unsigned short* Wlo = Whi + 122880;
  unsigned short* Kbt = (unsigned short*)regionC;               // decode: 64 MiB
  float* lastH = regionC + 16777216;                            // +64 MiB, 256 KiB

  prep_split<<<dim3(480), dim3(256), 0, stream>>>(ewih[0], ewih[1], ewih[2], Whi, Wlo);

  rec_fused<1><<<dim3(256), dim3(512), 0, stream>>>(
      x, nullptr, nullptr, Whi, Wlo,
      ewhh[0], ebih[0], ebhh[0], Hhi, Hlo);
  rec_fused<0><<<dim3(256), dim3(512), 0, stream>>>(
      nullptr, Hhi, Hlo, Whi + 24576, Wlo + 24576,
      ewhh[1], ebih[1], ebhh[1], Hhi, Hlo);
  rec_fused<0><<<dim3(256), dim3(512), 0, stream>>>(
      nullptr, Hhi, Hlo, Whi + 73728, Wlo + 73728,
      ewhh[2], ebih[2], ebhh[2], Hhi, Hlo);

  keys_gemm<<<dim3(4096), dim3(256), 0, stream>>>(Hhi, Hlo, aWk, abk, Kbt);
  save_lasth<<<dim3(128), dim3(512), 0, stream>>>(Hhi, Hlo, lastH);
  // Hlo is dead after keys_gemm + save_lasth: recycle it as H_bt (B,T,H)
  transpose_h<<<dim3(4096), dim3(256), 0, stream>>>(Hhi, Hlo);
  decoder<<<dim3(512), dim3(512), 0, stream>>>(
      Hlo, Kbt, lastH, aWq, abq, av, dwih, dwhh, dbih, dbhh,
      lng, lnb, w1, b1, w2, b2, (float*)d_out);
}